// Round 1
// baseline (3023.936 us; speedup 1.0000x reference)
//
#include <hip/hip_runtime.h>
#include <math.h>

constexpr int D_DIM  = 2048;   // feature dim (FFT length)
constexpr int HALF_D = 1024;
constexpr int B_DIM  = 2;
constexpr int S_DIM  = 4096;
constexpr int NROW   = B_DIM * S_DIM;      // 8192
constexpr int NCHUNK = 64;                 // scan chunks along S
constexpr int CHLEN  = S_DIM / NCHUNK;     // 64
constexpr float EPS_ = 1e-8f;

__device__ __forceinline__ float2 mkf2(float x, float y){ float2 r; r.x=x; r.y=y; return r; }
__device__ __forceinline__ float2 cmulf(float2 a, float2 b){
  return mkf2(fmaf(a.x, b.x, -a.y*b.y), fmaf(a.x, b.y, a.y*b.x));
}

// ---------------------------------------------------------------- GEMM ----
// C[M,N] = A[M,K] @ W[N,K]^T + bias[N]   (fp32, 128x128x16 tiles, 8x8 micro)
__global__ __launch_bounds__(256)
void gemm_nt_f32(const float* __restrict__ A, const float* __restrict__ W,
                 const float* __restrict__ bias, float* __restrict__ C,
                 int M, int N, int K)
{
  constexpr int BM = 128, BN = 128, BK = 16;
  __shared__ float As[BK][BM + 4];
  __shared__ float Bs[BK][BN + 4];
  const int tid = threadIdx.x;
  const int tx = tid & 15, ty = tid >> 4;
  const int bm = blockIdx.x * BM, bn = blockIdx.y * BN;

  float acc[8][8];
#pragma unroll
  for (int i = 0; i < 8; ++i)
#pragma unroll
    for (int j = 0; j < 8; ++j) acc[i][j] = 0.f;

  for (int k0 = 0; k0 < K; k0 += BK) {
#pragma unroll
    for (int rep = 0; rep < 2; ++rep) {
      int lin = tid + rep * 256;          // 0..511
      int r = lin >> 2, c = (lin & 3) * 4;
      float4 av = *(const float4*)(A + (size_t)(bm + r) * K + k0 + c);
      As[c+0][r] = av.x; As[c+1][r] = av.y; As[c+2][r] = av.z; As[c+3][r] = av.w;
      float4 wv = *(const float4*)(W + (size_t)(bn + r) * K + k0 + c);
      Bs[c+0][r] = wv.x; Bs[c+1][r] = wv.y; Bs[c+2][r] = wv.z; Bs[c+3][r] = wv.w;
    }
    __syncthreads();
#pragma unroll
    for (int k = 0; k < BK; ++k) {
      float4 a0 = *(const float4*)&As[k][ty*8];
      float4 a1 = *(const float4*)&As[k][ty*8+4];
      float4 b0 = *(const float4*)&Bs[k][tx*8];
      float4 b1 = *(const float4*)&Bs[k][tx*8+4];
      float ar[8] = {a0.x,a0.y,a0.z,a0.w,a1.x,a1.y,a1.z,a1.w};
      float br[8] = {b0.x,b0.y,b0.z,b0.w,b1.x,b1.y,b1.z,b1.w};
#pragma unroll
      for (int i = 0; i < 8; ++i)
#pragma unroll
        for (int j = 0; j < 8; ++j)
          acc[i][j] = fmaf(ar[i], br[j], acc[i][j]);
    }
    __syncthreads();
  }

#pragma unroll
  for (int i = 0; i < 8; ++i) {
    int row = bm + ty*8 + i;
#pragma unroll
    for (int j = 0; j < 8; j += 4) {
      int col = bn + tx*8 + j;
      float4 o;
      o.x = acc[i][j+0] + bias[col+0];
      o.y = acc[i][j+1] + bias[col+1];
      o.z = acc[i][j+2] + bias[col+2];
      o.w = acc[i][j+3] + bias[col+3];
      *(float4*)(C + (size_t)row * N + col) = o;
    }
  }
}

// ------------------------------------------------------------- FFT core ---
// Radix-2 DIT, 2048-pt, input must already be bit-reverse permuted in LDS.
// tw[k] = exp(-2*pi*i*k/2048), k=0..1023.  INV=1: conj twiddles (no 1/N).
template<int INV>
__device__ void fft2048(float2* X, const float2* tw, int tid)
{
#pragma unroll
  for (int s = 0; s < 11; ++s) {
    const int m = 1 << s;
    __syncthreads();
#pragma unroll 4
    for (int t = tid; t < 1024; t += 256) {
      int j = t & (m - 1);
      int base = ((t >> s) << (s + 1)) + j;
      float2 w = tw[j << (10 - s)];
      if (INV) w.y = -w.y;
      float2 u = X[base];
      float2 v = cmulf(w, X[base + m]);
      X[base]     = mkf2(u.x + v.x, u.y + v.y);
      X[base + m] = mkf2(u.x - v.x, u.y - v.y);
    }
  }
  __syncthreads();
}

__device__ __forceinline__ void load_twiddles(float2* tw, int tid)
{
  for (int i = tid; i < HALF_D; i += 256) {
    float sv, cv;
    sincosf(-6.283185307179586f * (float)i / (float)D_DIM, &sv, &cv);
    tw[i] = mkf2(cv, sv);
  }
}

// ---------------------------------------------------------- FFT(k,v)·mul --
// Reads k row (kbuf) and v row (vbuf); writes packed half-spectrum of
// unit(Fk)*unit(Fv) over the k row: bin d=1..1023 complex; bin0 = (P[0].re,
// P[1024].re)  (both purely real by conj symmetry).
__global__ __launch_bounds__(256)
void fftkv_kernel(float* __restrict__ kbuf, const float* __restrict__ vbuf)
{
  __shared__ float2 tw[HALF_D];
  __shared__ float2 Xa[D_DIM];
  __shared__ float2 Xb[D_DIM];
  const int tid = threadIdx.x;
  const size_t row = blockIdx.x;
  const float* krow = kbuf + row * D_DIM;
  const float* vrow = vbuf + row * D_DIM;

  load_twiddles(tw, tid);
  for (int i = tid; i < D_DIM; i += 256) {
    int r = __brev((unsigned)i) >> 21;
    Xa[r] = mkf2(krow[i], 0.f);
    Xb[r] = mkf2(vrow[i], 0.f);
  }
  fft2048<0>(Xa, tw, tid);
  fft2048<0>(Xb, tw, tid);

  float2* outp = (float2*)(kbuf + row * D_DIM);
  for (int d = tid; d < HALF_D; d += 256) {
    float2 a = Xa[d], b = Xb[d];
    float sa = 1.f / (sqrtf(a.x*a.x + a.y*a.y) + EPS_);
    float sb = 1.f / (sqrtf(b.x*b.x + b.y*b.y) + EPS_);
    float2 p = cmulf(a, b);
    float sc = sa * sb;
    p.x *= sc; p.y *= sc;
    if (d == 0) {
      float2 an = Xa[HALF_D], bn = Xb[HALF_D];
      float na = 1.f / (sqrtf(an.x*an.x + an.y*an.y) + EPS_);
      float nb = 1.f / (sqrtf(bn.x*bn.x + bn.y*bn.y) + EPS_);
      float2 pn = cmulf(an, bn);
      p = mkf2(p.x, pn.x * na * nb);
    }
    outp[d] = p;
  }
}

// --------------------------------------------------------------- scan -----
// Inclusive cumsum along S (per batch, per freq bin), on packed spectra.
// Phase 1: per-chunk sums.  Phase 2: exclusive scan of chunk sums.
// Phase 3: apply offsets + in-chunk inclusive scan, in place.
__global__ __launch_bounds__(256)
void scan_partial(const float2* __restrict__ kv, float2* __restrict__ part)
{
  int gid = blockIdx.x * 256 + threadIdx.x;        // 0 .. B*NCHUNK*HALF_D-1
  int d = gid & (HALF_D - 1);
  int chunk = (gid >> 10) & (NCHUNK - 1);
  int b = gid >> 16;
  const float2* p = kv + ((size_t)(b * S_DIM + chunk * CHLEN) * HALF_D) + d;
  float2 acc = mkf2(0.f, 0.f);
  for (int s = 0; s < CHLEN; ++s) {
    float2 v = p[(size_t)s * HALF_D];
    acc.x += v.x; acc.y += v.y;
  }
  part[gid] = acc;                                  // layout [b][chunk][d]
}

__global__ __launch_bounds__(256)
void scan_offsets(float2* __restrict__ part)
{
  int gid = blockIdx.x * 256 + threadIdx.x;        // 0 .. B*HALF_D-1
  int d = gid & (HALF_D - 1);
  int b = gid >> 10;
  float2* p = part + (size_t)b * (NCHUNK * HALF_D) + d;
  float2 acc = mkf2(0.f, 0.f);
  for (int c = 0; c < NCHUNK; ++c) {
    float2 v = p[(size_t)c * HALF_D];
    p[(size_t)c * HALF_D] = acc;                   // exclusive prefix
    acc.x += v.x; acc.y += v.y;
  }
}

__global__ __launch_bounds__(256)
void scan_apply(float2* __restrict__ kv, const float2* __restrict__ part)
{
  int gid = blockIdx.x * 256 + threadIdx.x;
  int d = gid & (HALF_D - 1);
  int chunk = (gid >> 10) & (NCHUNK - 1);
  int b = gid >> 16;
  float2* p = kv + ((size_t)(b * S_DIM + chunk * CHLEN) * HALF_D) + d;
  float2 acc = part[gid];
  for (int s = 0; s < CHLEN; ++s) {
    float2 v = p[(size_t)s * HALF_D];
    acc.x += v.x; acc.y += v.y;
    p[(size_t)s * HALF_D] = acc;
  }
}

// --------------------------------------------------------------- final ----
// out = base + gate * real(ifft(conj(Fq) * Fmem)).  q lives in d_out (read
// first, overwritten at the end); Fmem is the scanned packed spectrum.
__global__ __launch_bounds__(256)
void final_kernel(float* __restrict__ qo, const float2* __restrict__ mem,
                  const float* __restrict__ base, const float* __restrict__ gate)
{
  __shared__ float2 tw[HALF_D];
  __shared__ float2 Xa[D_DIM];
  __shared__ float2 Xb[D_DIM];
  __shared__ float2 Fm[HALF_D];
  const int tid = threadIdx.x;
  const size_t row = blockIdx.x;
  float* qrow = qo + row * D_DIM;
  const float2* mrow = mem + row * HALF_D;

  load_twiddles(tw, tid);
  for (int i = tid; i < HALF_D; i += 256) Fm[i] = mrow[i];
  for (int i = tid; i < D_DIM; i += 256) {
    int r = __brev((unsigned)i) >> 21;
    Xa[r] = mkf2(qrow[i], 0.f);
  }
  fft2048<0>(Xa, tw, tid);

  // G = conj(Fq) * Fmem  (full spectrum via conj symmetry), bit-rev into Xb
  for (int d2 = tid; d2 < D_DIM; d2 += 256) {
    float2 fm;
    if (d2 == 0)            fm = mkf2(Fm[0].x, 0.f);
    else if (d2 == HALF_D)  fm = mkf2(Fm[0].y, 0.f);
    else if (d2 < HALF_D)   fm = Fm[d2];
    else { float2 c = Fm[D_DIM - d2]; fm = mkf2(c.x, -c.y); }
    float2 fq = Xa[d2];
    float2 g = cmulf(mkf2(fq.x, -fq.y), fm);
    Xb[__brev((unsigned)d2) >> 21] = g;
  }
  fft2048<1>(Xb, tw, tid);

  const float gv = gate[0] * (1.f / (float)D_DIM);
  const float* brow = base + row * D_DIM;
  for (int i = tid; i < D_DIM; i += 256) {
    qrow[i] = brow[i] + gv * Xb[i].x;
  }
}

// ------------------------------------------------------------ launcher ----
extern "C" void kernel_launch(void* const* d_in, const int* in_sizes, int n_in,
                              void* d_out, int out_size, void* d_ws, size_t ws_size,
                              hipStream_t stream)
{
  const float* hs   = (const float*)d_in[0];
  const float* base = (const float*)d_in[1];
  const float* Wq   = (const float*)d_in[2];
  const float* bq   = (const float*)d_in[3];
  const float* Wk   = (const float*)d_in[4];
  const float* bk   = (const float*)d_in[5];
  const float* Wv   = (const float*)d_in[6];
  const float* bv   = (const float*)d_in[7];
  const float* gate = (const float*)d_in[8];
  float* out  = (float*)d_out;

  // workspace: k rows (64MB, later overwritten by packed Fkv / scanned Fmem),
  //            v rows (64MB), chunk partials (1MB)
  float*  kbuf = (float*)d_ws;
  float*  vbuf = kbuf + (size_t)NROW * D_DIM;
  float2* part = (float2*)(vbuf + (size_t)NROW * D_DIM);

  dim3 gg(NROW / 128, D_DIM / 128);
  gemm_nt_f32<<<gg, 256, 0, stream>>>(hs, Wq, bq, out,  NROW, D_DIM, D_DIM);
  gemm_nt_f32<<<gg, 256, 0, stream>>>(hs, Wk, bk, kbuf, NROW, D_DIM, D_DIM);
  gemm_nt_f32<<<gg, 256, 0, stream>>>(hs, Wv, bv, vbuf, NROW, D_DIM, D_DIM);

  fftkv_kernel<<<NROW, 256, 0, stream>>>(kbuf, vbuf);

  scan_partial<<<(B_DIM * NCHUNK * HALF_D) / 256, 256, 0, stream>>>(
      (const float2*)kbuf, part);
  scan_offsets<<<(B_DIM * HALF_D) / 256, 256, 0, stream>>>(part);
  scan_apply<<<(B_DIM * NCHUNK * HALF_D) / 256, 256, 0, stream>>>(
      (float2*)kbuf, part);

  final_kernel<<<NROW, 256, 0, stream>>>(out, (const float2*)kbuf, base, gate);
}

// Round 2
// 771.325 us; speedup vs baseline: 3.9204x; 3.9204x over previous
//
#include <hip/hip_runtime.h>
#include <math.h>

constexpr int D_DIM  = 2048;   // feature dim (FFT length)
constexpr int HALF_D = 1024;
constexpr int B_DIM  = 2;
constexpr int S_DIM  = 4096;
constexpr int NROW   = B_DIM * S_DIM;      // 8192
constexpr int NCHUNK = 64;                 // scan chunks along S
constexpr int CHLEN  = S_DIM / NCHUNK;     // 64
constexpr float EPS_ = 1e-8f;

typedef __attribute__((ext_vector_type(8))) short  short8;   // bf16x8 frag
typedef __attribute__((ext_vector_type(8))) unsigned short ushort8;
typedef __attribute__((ext_vector_type(4))) float  f32x4;    // MFMA acc

__device__ __forceinline__ float2 mkf2(float x, float y){ float2 r; r.x=x; r.y=y; return r; }
__device__ __forceinline__ float2 cmulf(float2 a, float2 b){
  return mkf2(fmaf(a.x, b.x, -a.y*b.y), fmaf(a.x, b.y, a.y*b.x));
}
__device__ __forceinline__ unsigned short f2bf(float x){
  unsigned u = __float_as_uint(x);
  u += 0x7fff + ((u >> 16) & 1);           // round-to-nearest-even
  return (unsigned short)(u >> 16);
}
__device__ __forceinline__ float bf2f(unsigned short h){
  return __uint_as_float(((unsigned)h) << 16);
}

// ------------------------------------------------------------ fp32→bf16 ---
__global__ __launch_bounds__(256)
void cvt_f32_bf16(const float* __restrict__ in, unsigned short* __restrict__ out, int n8)
{
  int i = blockIdx.x * 256 + threadIdx.x;
  if (i >= n8) return;
  const float4* p = (const float4*)in + (size_t)i * 2;
  float4 a = p[0], b = p[1];
  ushort8 o;
  o[0]=f2bf(a.x); o[1]=f2bf(a.y); o[2]=f2bf(a.z); o[3]=f2bf(a.w);
  o[4]=f2bf(b.x); o[5]=f2bf(b.y); o[6]=f2bf(b.z); o[7]=f2bf(b.w);
  *(ushort8*)(out + (size_t)i * 8) = o;
}

// ---------------------------------------------------------- bf16 MFMA GEMM
// C[M,N] = A[M,K] @ W[N,K]^T + bias[N].  A,W bf16 row-major; C fp32 or bf16.
// 128x128 tile, BK=32, 4 waves (2x2), each wave 64x64 = 4x4 x (16x16) frags.
template<int OUT_BF16>
__global__ __launch_bounds__(256)
void gemm_mfma_bf16(const unsigned short* __restrict__ A,
                    const unsigned short* __restrict__ W,
                    const float* __restrict__ bias, void* __restrict__ Cout,
                    int M, int N, int K)
{
  constexpr int BM = 128, BN = 128, BK = 32;
  __shared__ unsigned short Asm[BM * BK];   // row-major [128][32]
  __shared__ unsigned short Bsm[BN * BK];   // row-major [128][32] (N-major)
  const int tid  = threadIdx.x;
  const int wid  = tid >> 6, lane = tid & 63;
  const int bm   = blockIdx.x * BM, bn = blockIdx.y * BN;
  const int wr   = wid >> 1, wc = wid & 1;          // wave 64x64 sub-tile

  f32x4 acc[4][4];
#pragma unroll
  for (int i = 0; i < 4; ++i)
#pragma unroll
    for (int j = 0; j < 4; ++j) acc[i][j] = (f32x4){0.f, 0.f, 0.f, 0.f};

  // staging coords: chunk = 16 rows x 32 cols = 1024B; wave w stages chunks
  // {2w, 2w+1} of each tile; lane covers row chunk*16+lane/4, k (lane%4)*8.
  const int srow = lane >> 2;
  const int skof = (lane & 3) * 8;
  // fragment read coords
  const int fr = lane & 15;
  const int fk = (lane >> 4) * 8;

  for (int k0 = 0; k0 < K; k0 += BK) {
#pragma unroll
    for (int cc = 0; cc < 2; ++cc) {
      int c = 2 * wid + cc;
      __builtin_amdgcn_global_load_lds(
        (const __attribute__((address_space(1))) void*)
          (A + (size_t)(bm + c * 16 + srow) * K + k0 + skof),
        (__attribute__((address_space(3))) void*)(&Asm[c * 512]), 16, 0, 0);
      __builtin_amdgcn_global_load_lds(
        (const __attribute__((address_space(1))) void*)
          (W + (size_t)(bn + c * 16 + srow) * K + k0 + skof),
        (__attribute__((address_space(3))) void*)(&Bsm[c * 512]), 16, 0, 0);
    }
    __syncthreads();   // drains vmcnt, staging visible

    short8 af[4], bf[4];
#pragma unroll
    for (int i = 0; i < 4; ++i)
      af[i] = *(const short8*)&Asm[(wr * 64 + i * 16 + fr) * BK + fk];
#pragma unroll
    for (int j = 0; j < 4; ++j)
      bf[j] = *(const short8*)&Bsm[(wc * 64 + j * 16 + fr) * BK + fk];
#pragma unroll
    for (int i = 0; i < 4; ++i)
#pragma unroll
      for (int j = 0; j < 4; ++j)
        acc[i][j] = __builtin_amdgcn_mfma_f32_16x16x32_bf16(af[i], bf[j], acc[i][j], 0, 0, 0);
    __syncthreads();   // protect LDS before next stage overwrites
  }

  // epilogue: C row = (lane>>4)*4 + r (M side), col = lane&15 (N side)
  const int er4 = (lane >> 4) * 4;
  const int ec  = lane & 15;
  float bv[4];
#pragma unroll
  for (int j = 0; j < 4; ++j) bv[j] = bias[bn + wc * 64 + j * 16 + ec];
#pragma unroll
  for (int i = 0; i < 4; ++i) {
#pragma unroll
    for (int j = 0; j < 4; ++j) {
      int col = bn + wc * 64 + j * 16 + ec;
#pragma unroll
      for (int r = 0; r < 4; ++r) {
        int row = bm + wr * 64 + i * 16 + er4 + r;
        float val = acc[i][j][r] + bv[j];
        if (OUT_BF16)
          ((unsigned short*)Cout)[(size_t)row * N + col] = f2bf(val);
        else
          ((float*)Cout)[(size_t)row * N + col] = val;
      }
    }
  }
}

// ------------------------------------------------------------- FFT core ---
// Radix-2 DIT, 2048-pt, input must already be bit-reverse permuted in LDS.
// tw[k] = exp(-2*pi*i*k/2048), k=0..1023.  INV=1: conj twiddles (no 1/N).
template<int INV>
__device__ void fft2048(float2* X, const float2* tw, int tid)
{
#pragma unroll
  for (int s = 0; s < 11; ++s) {
    const int m = 1 << s;
    __syncthreads();
#pragma unroll 4
    for (int t = tid; t < 1024; t += 256) {
      int j = t & (m - 1);
      int base = ((t >> s) << (s + 1)) + j;
      float2 w = tw[j << (10 - s)];
      if (INV) w.y = -w.y;
      float2 u = X[base];
      float2 v = cmulf(w, X[base + m]);
      X[base]     = mkf2(u.x + v.x, u.y + v.y);
      X[base + m] = mkf2(u.x - v.x, u.y - v.y);
    }
  }
  __syncthreads();
}

__device__ __forceinline__ void load_twiddles(float2* tw, int tid)
{
  for (int i = tid; i < HALF_D; i += 256) {
    float sv, cv;
    sincosf(-6.283185307179586f * (float)i / (float)D_DIM, &sv, &cv);
    tw[i] = mkf2(cv, sv);
  }
}

// ---------------------------------------------------------- FFT(k,v)·mul --
// One complex FFT of (k + i·v) recovers both real-input spectra:
//   Fk[d] = (Z[d] + conj(Z[N-d]))/2,  Fv[d] = -i·(Z[d] - conj(Z[N-d]))/2.
// Writes packed half-spectrum of unit(Fk)·unit(Fv) over the k row:
// bins 1..1023 complex; bin0 = (P[0].re, P[1024].re).
__global__ __launch_bounds__(256)
void fftkv_kernel(float* __restrict__ kbuf, const unsigned short* __restrict__ vbuf)
{
  __shared__ float2 tw[HALF_D];
  __shared__ float2 X[D_DIM];
  const int tid = threadIdx.x;
  const size_t row = blockIdx.x;
  const float* krow = kbuf + row * D_DIM;
  const unsigned short* vrow = vbuf + row * D_DIM;

  load_twiddles(tw, tid);
  for (int i = tid; i < D_DIM; i += 256) {
    int r = __brev((unsigned)i) >> 21;
    X[r] = mkf2(krow[i], bf2f(vrow[i]));
  }
  fft2048<0>(X, tw, tid);

  float2* outp = (float2*)(kbuf + row * D_DIM);
  for (int d = tid; d < HALF_D; d += 256) {
    float2 p;
    if (d == 0) {
      // bin 0 and bin 1024 are purely real
      float k0 = X[0].x, v0 = X[0].y;
      float kn = X[HALF_D].x, vn = X[HALF_D].y;
      float p0 = (k0 / (fabsf(k0) + EPS_)) * (v0 / (fabsf(v0) + EPS_));
      float pn = (kn / (fabsf(kn) + EPS_)) * (vn / (fabsf(vn) + EPS_));
      p = mkf2(p0, pn);
    } else {
      float2 A = X[d];
      float2 Bc = X[D_DIM - d];            // Z[N-d]
      float2 Bj = mkf2(Bc.x, -Bc.y);       // conj
      float2 Fk = mkf2(0.5f * (A.x + Bj.x), 0.5f * (A.y + Bj.y));
      float2 t  = mkf2(0.5f * (A.x - Bj.x), 0.5f * (A.y - Bj.y));
      float2 Fv = mkf2(t.y, -t.x);         // -i * t
      float sa = 1.f / (sqrtf(Fk.x*Fk.x + Fk.y*Fk.y) + EPS_);
      float sb = 1.f / (sqrtf(Fv.x*Fv.x + Fv.y*Fv.y) + EPS_);
      p = cmulf(Fk, Fv);
      float sc = sa * sb;
      p.x *= sc; p.y *= sc;
    }
    outp[d] = p;
  }
}

// --------------------------------------------------------------- scan -----
__global__ __launch_bounds__(256)
void scan_partial(const float2* __restrict__ kv, float2* __restrict__ part)
{
  int gid = blockIdx.x * 256 + threadIdx.x;        // 0 .. B*NCHUNK*HALF_D-1
  int d = gid & (HALF_D - 1);
  int chunk = (gid >> 10) & (NCHUNK - 1);
  int b = gid >> 16;
  const float2* p = kv + ((size_t)(b * S_DIM + chunk * CHLEN) * HALF_D) + d;
  float2 acc = mkf2(0.f, 0.f);
  for (int s = 0; s < CHLEN; ++s) {
    float2 v = p[(size_t)s * HALF_D];
    acc.x += v.x; acc.y += v.y;
  }
  part[gid] = acc;                                  // layout [b][chunk][d]
}

__global__ __launch_bounds__(256)
void scan_offsets(float2* __restrict__ part)
{
  int gid = blockIdx.x * 256 + threadIdx.x;        // 0 .. B*HALF_D-1
  int d = gid & (HALF_D - 1);
  int b = gid >> 10;
  float2* p = part + (size_t)b * (NCHUNK * HALF_D) + d;
  float2 acc = mkf2(0.f, 0.f);
  for (int c = 0; c < NCHUNK; ++c) {
    float2 v = p[(size_t)c * HALF_D];
    p[(size_t)c * HALF_D] = acc;                   // exclusive prefix
    acc.x += v.x; acc.y += v.y;
  }
}

__global__ __launch_bounds__(256)
void scan_apply(float2* __restrict__ kv, const float2* __restrict__ part)
{
  int gid = blockIdx.x * 256 + threadIdx.x;
  int d = gid & (HALF_D - 1);
  int chunk = (gid >> 10) & (NCHUNK - 1);
  int b = gid >> 16;
  float2* p = kv + ((size_t)(b * S_DIM + chunk * CHLEN) * HALF_D) + d;
  float2 acc = part[gid];
  for (int s = 0; s < CHLEN; ++s) {
    float2 v = p[(size_t)s * HALF_D];
    acc.x += v.x; acc.y += v.y;
    p[(size_t)s * HALF_D] = acc;
  }
}

// --------------------------------------------------------------- final ----
// out = base + gate * real(ifft(conj(Fq) * Fmem)).  q lives in d_out (read
// first, overwritten at the end); Fmem is the scanned packed spectrum.
__global__ __launch_bounds__(256)
void final_kernel(float* __restrict__ qo, const float2* __restrict__ mem,
                  const float* __restrict__ base, const float* __restrict__ gate)
{
  __shared__ float2 tw[HALF_D];
  __shared__ float2 Xa[D_DIM];
  __shared__ float2 Xb[D_DIM];
  __shared__ float2 Fm[HALF_D];
  const int tid = threadIdx.x;
  const size_t row = blockIdx.x;
  float* qrow = qo + row * D_DIM;
  const float2* mrow = mem + row * HALF_D;

  load_twiddles(tw, tid);
  for (int i = tid; i < HALF_D; i += 256) Fm[i] = mrow[i];
  for (int i = tid; i < D_DIM; i += 256) {
    int r = __brev((unsigned)i) >> 21;
    Xa[r] = mkf2(qrow[i], 0.f);
  }
  fft2048<0>(Xa, tw, tid);

  // G = conj(Fq) * Fmem  (full spectrum via conj symmetry), bit-rev into Xb
  for (int d2 = tid; d2 < D_DIM; d2 += 256) {
    float2 fm;
    if (d2 == 0)            fm = mkf2(Fm[0].x, 0.f);
    else if (d2 == HALF_D)  fm = mkf2(Fm[0].y, 0.f);
    else if (d2 < HALF_D)   fm = Fm[d2];
    else { float2 c = Fm[D_DIM - d2]; fm = mkf2(c.x, -c.y); }
    float2 fq = Xa[d2];
    float2 g = cmulf(mkf2(fq.x, -fq.y), fm);
    Xb[__brev((unsigned)d2) >> 21] = g;
  }
  fft2048<1>(Xb, tw, tid);

  const float gv = gate[0] * (1.f / (float)D_DIM);
  const float* brow = base + row * D_DIM;
  for (int i = tid; i < D_DIM; i += 256) {
    qrow[i] = brow[i] + gv * Xb[i].x;
  }
}

// ------------------------------------------------------------ launcher ----
extern "C" void kernel_launch(void* const* d_in, const int* in_sizes, int n_in,
                              void* d_out, int out_size, void* d_ws, size_t ws_size,
                              hipStream_t stream)
{
  const float* hs   = (const float*)d_in[0];
  const float* base = (const float*)d_in[1];
  const float* Wq   = (const float*)d_in[2];
  const float* bq   = (const float*)d_in[3];
  const float* Wk   = (const float*)d_in[4];
  const float* bk   = (const float*)d_in[5];
  const float* Wv   = (const float*)d_in[6];
  const float* bv   = (const float*)d_in[7];
  const float* gate = (const float*)d_in[8];
  float* out  = (float*)d_out;

  // workspace layout (160.4 MB):
  //   hsb  bf16 [8192][2048]                    33.5 MB
  //   wqb/wkb/wvb bf16 [2048][2048] x3          25.2 MB
  //   kbuf f32  [8192][2048] (→ packed Fkv/Fmem)67.1 MB
  //   vbuf bf16 [8192][2048]                    33.5 MB
  //   part f32x2 [2][64][1024]                   1.0 MB
  char* ws = (char*)d_ws;
  unsigned short* hsb = (unsigned short*)ws;
  unsigned short* wqb = (unsigned short*)(ws + 33554432);
  unsigned short* wkb = wqb + (size_t)D_DIM * D_DIM;
  unsigned short* wvb = wkb + (size_t)D_DIM * D_DIM;
  float*  kbuf = (float*)(ws + 58720256);
  unsigned short* vbuf = (unsigned short*)(ws + 58720256 + 67108864);
  float2* part = (float2*)(ws + 58720256 + 67108864 + 33554432);

  // fp32 -> bf16 conversions
  {
    int n8 = (NROW * D_DIM) / 8;                  // 2,097,152
    cvt_f32_bf16<<<n8 / 256, 256, 0, stream>>>(hs, hsb, n8);
    int w8 = (D_DIM * D_DIM) / 8;                 // 524,288
    cvt_f32_bf16<<<w8 / 256, 256, 0, stream>>>(Wq, wqb, w8);
    cvt_f32_bf16<<<w8 / 256, 256, 0, stream>>>(Wk, wkb, w8);
    cvt_f32_bf16<<<w8 / 256, 256, 0, stream>>>(Wv, wvb, w8);
  }

  dim3 gg(NROW / 128, D_DIM / 128);
  gemm_mfma_bf16<0><<<gg, 256, 0, stream>>>(hsb, wqb, bq, out,  NROW, D_DIM, D_DIM);
  gemm_mfma_bf16<0><<<gg, 256, 0, stream>>>(hsb, wkb, bk, kbuf, NROW, D_DIM, D_DIM);
  gemm_mfma_bf16<1><<<gg, 256, 0, stream>>>(hsb, wvb, bv, vbuf, NROW, D_DIM, D_DIM);

  fftkv_kernel<<<NROW, 256, 0, stream>>>(kbuf, vbuf);

  scan_partial<<<(B_DIM * NCHUNK * HALF_D) / 256, 256, 0, stream>>>(
      (const float2*)kbuf, part);
  scan_offsets<<<(B_DIM * HALF_D) / 256, 256, 0, stream>>>(part);
  scan_apply<<<(B_DIM * NCHUNK * HALF_D) / 256, 256, 0, stream>>>(
      (float2*)kbuf, part);

  final_kernel<<<NROW, 256, 0, stream>>>(out, (const float2*)kbuf, base, gate);
}

// Round 3
// 545.080 us; speedup vs baseline: 5.5477x; 1.4151x over previous
//
#include <hip/hip_runtime.h>
#include <math.h>

constexpr int D_DIM  = 2048;   // feature dim (FFT length)
constexpr int HALF_D = 1024;
constexpr int B_DIM  = 2;
constexpr int S_DIM  = 4096;
constexpr int NROW   = B_DIM * S_DIM;      // 8192
constexpr int NCHUNK = 64;                 // scan chunks along S
constexpr int CHLEN  = S_DIM / NCHUNK;     // 64
constexpr float EPS_ = 1e-8f;

typedef __attribute__((ext_vector_type(8))) short  short8;   // bf16x8 frag
typedef __attribute__((ext_vector_type(8))) unsigned short ushort8;
typedef __attribute__((ext_vector_type(4))) float  f32x4;    // MFMA acc

__device__ __forceinline__ float2 mkf2(float x, float y){ float2 r; r.x=x; r.y=y; return r; }
__device__ __forceinline__ float2 cmulf(float2 a, float2 b){
  return mkf2(fmaf(a.x, b.x, -a.y*b.y), fmaf(a.x, b.y, a.y*b.x));
}
__device__ __forceinline__ unsigned short f2bf(float x){
  unsigned u = __float_as_uint(x);
  u += 0x7fff + ((u >> 16) & 1);           // round-to-nearest-even
  return (unsigned short)(u >> 16);
}
__device__ __forceinline__ float bf2f(unsigned short h){
  return __uint_as_float(((unsigned)h) << 16);
}

// ------------------------------------------------------------ fp32→bf16 ---
__global__ __launch_bounds__(256)
void cvt_f32_bf16(const float* __restrict__ in, unsigned short* __restrict__ out, int n8)
{
  int i = blockIdx.x * 256 + threadIdx.x;
  if (i >= n8) return;
  const float4* p = (const float4*)in + (size_t)i * 2;
  float4 a = p[0], b = p[1];
  ushort8 o;
  o[0]=f2bf(a.x); o[1]=f2bf(a.y); o[2]=f2bf(a.z); o[3]=f2bf(a.w);
  o[4]=f2bf(b.x); o[5]=f2bf(b.y); o[6]=f2bf(b.z); o[7]=f2bf(b.w);
  *(ushort8*)(out + (size_t)i * 8) = o;
}

// ---------------------------------------------------------- bf16 MFMA GEMM
template<int OUT_BF16>
__global__ __launch_bounds__(256)
void gemm_mfma_bf16(const unsigned short* __restrict__ A,
                    const unsigned short* __restrict__ W,
                    const float* __restrict__ bias, void* __restrict__ Cout,
                    int M, int N, int K)
{
  constexpr int BM = 128, BN = 128, BK = 32;
  __shared__ unsigned short Asm[BM * BK];   // row-major [128][32]
  __shared__ unsigned short Bsm[BN * BK];   // row-major [128][32] (N-major)
  const int tid  = threadIdx.x;
  const int wid  = tid >> 6, lane = tid & 63;
  const int bm   = blockIdx.x * BM, bn = blockIdx.y * BN;
  const int wr   = wid >> 1, wc = wid & 1;          // wave 64x64 sub-tile

  f32x4 acc[4][4];
#pragma unroll
  for (int i = 0; i < 4; ++i)
#pragma unroll
    for (int j = 0; j < 4; ++j) acc[i][j] = (f32x4){0.f, 0.f, 0.f, 0.f};

  const int srow = lane >> 2;
  const int skof = (lane & 3) * 8;
  const int fr = lane & 15;
  const int fk = (lane >> 4) * 8;

  for (int k0 = 0; k0 < K; k0 += BK) {
#pragma unroll
    for (int cc = 0; cc < 2; ++cc) {
      int c = 2 * wid + cc;
      __builtin_amdgcn_global_load_lds(
        (const __attribute__((address_space(1))) void*)
          (A + (size_t)(bm + c * 16 + srow) * K + k0 + skof),
        (__attribute__((address_space(3))) void*)(&Asm[c * 512]), 16, 0, 0);
      __builtin_amdgcn_global_load_lds(
        (const __attribute__((address_space(1))) void*)
          (W + (size_t)(bn + c * 16 + srow) * K + k0 + skof),
        (__attribute__((address_space(3))) void*)(&Bsm[c * 512]), 16, 0, 0);
    }
    __syncthreads();

    short8 af[4], bf[4];
#pragma unroll
    for (int i = 0; i < 4; ++i)
      af[i] = *(const short8*)&Asm[(wr * 64 + i * 16 + fr) * BK + fk];
#pragma unroll
    for (int j = 0; j < 4; ++j)
      bf[j] = *(const short8*)&Bsm[(wc * 64 + j * 16 + fr) * BK + fk];
#pragma unroll
    for (int i = 0; i < 4; ++i)
#pragma unroll
      for (int j = 0; j < 4; ++j)
        acc[i][j] = __builtin_amdgcn_mfma_f32_16x16x32_bf16(af[i], bf[j], acc[i][j], 0, 0, 0);
    __syncthreads();
  }

  const int er4 = (lane >> 4) * 4;
  const int ec  = lane & 15;
  float bv[4];
#pragma unroll
  for (int j = 0; j < 4; ++j) bv[j] = bias[bn + wc * 64 + j * 16 + ec];
#pragma unroll
  for (int i = 0; i < 4; ++i) {
#pragma unroll
    for (int j = 0; j < 4; ++j) {
      int col = bn + wc * 64 + j * 16 + ec;
#pragma unroll
      for (int r = 0; r < 4; ++r) {
        int row = bm + wr * 64 + i * 16 + er4 + r;
        float val = acc[i][j][r] + bv[j];
        if (OUT_BF16)
          ((unsigned short*)Cout)[(size_t)row * N + col] = f2bf(val);
        else
          ((float*)Cout)[(size_t)row * N + col] = val;
      }
    }
  }
}

// ------------------------------------------------------------- FFT core ---
// 2048-pt FFT, 256 threads, radix 8-8-8-4 macro-stages, register butterflies.
// Data in LDS with XOR-fold swizzle (bank-conflict-free for all strides used).
// Forward: DIT, bit-reversed input scatter -> natural-order output.
// Inverse: DIF (transposed network, conj twiddles), natural input ->
// bit-reversed output (absorbed in final gather).

__device__ __forceinline__ int XS(int i){ return i ^ (((i >> 5) ^ (i >> 10)) & 31); }
__device__ __forceinline__ int TS(int i){ return i ^ ((i >> 5) & 31); }

__device__ __forceinline__ float2 mulmi(float2 w){ return mkf2(w.y, -w.x); }   // w * (-i)
__device__ __forceinline__ float2 mulw8(float2 w){                              // w * e^{-i pi/4}
  const float c = 0.70710678118654752f;
  return mkf2(c * (w.x + w.y), c * (w.y - w.x));
}
__device__ __forceinline__ void bfly(float2& a, float2& b, float2 w){
  float2 v = cmulf(w, b);
  b = mkf2(a.x - v.x, a.y - v.y);
  a = mkf2(a.x + v.x, a.y + v.y);
}
// inverse (transposed) butterfly: twiddle (conjugated) applied after subtract
__device__ __forceinline__ void bflyc(float2& a, float2& b, float2 w){
  float2 d = mkf2(a.x - b.x, a.y - b.y);
  a = mkf2(a.x + b.x, a.y + b.y);
  b = mkf2(fmaf(d.x, w.x, d.y * w.y), fmaf(d.y, w.x, -d.x * w.y));  // d * conj(w)
}

__device__ __forceinline__ void fwd8(float2 e[8], float2 wA, float2 wB0, float2 wC0){
  bfly(e[0], e[1], wA); bfly(e[2], e[3], wA); bfly(e[4], e[5], wA); bfly(e[6], e[7], wA);
  float2 wB1 = mulmi(wB0);
  bfly(e[0], e[2], wB0); bfly(e[1], e[3], wB1); bfly(e[4], e[6], wB0); bfly(e[5], e[7], wB1);
  float2 wC1 = mulw8(wC0), wC2 = mulmi(wC0), wC3 = mulmi(wC1);
  bfly(e[0], e[4], wC0); bfly(e[1], e[5], wC1); bfly(e[2], e[6], wC2); bfly(e[3], e[7], wC3);
}
__device__ __forceinline__ void inv8(float2 e[8], float2 wA, float2 wB0, float2 wC0){
  float2 wC1 = mulw8(wC0), wC2 = mulmi(wC0), wC3 = mulmi(wC1);
  bflyc(e[0], e[4], wC0); bflyc(e[1], e[5], wC1); bflyc(e[2], e[6], wC2); bflyc(e[3], e[7], wC3);
  float2 wB1 = mulmi(wB0);
  bflyc(e[0], e[2], wB0); bflyc(e[1], e[3], wB1); bflyc(e[4], e[6], wB0); bflyc(e[5], e[7], wB1);
  bflyc(e[0], e[1], wA); bflyc(e[2], e[3], wA); bflyc(e[4], e[5], wA); bflyc(e[6], e[7], wA);
}

__device__ __forceinline__ float2 twld(const float* twr, const float* twi, int i){
  int s = TS(i);
  return mkf2(twr[s], twi[s]);
}

__device__ void fft_fwd(float2* X, const float* twr, const float* twi, int t)
{
  const float2 one = mkf2(1.f, 0.f);
  {                                   // MS1: m=1, groups of 8 consecutive
    int b = 8 * t;
    float2 e[8];
#pragma unroll
    for (int r = 0; r < 8; ++r) e[r] = X[XS(b + r)];
    fwd8(e, one, one, one);
#pragma unroll
    for (int r = 0; r < 8; ++r) X[XS(b + r)] = e[r];
  }
  __syncthreads();
  {                                   // MS2: m=8, u=t>>5, G=t&31
    int u = t >> 5, b = 64 * (t & 31) + u;
    float2 e[8];
#pragma unroll
    for (int r = 0; r < 8; ++r) e[r] = X[XS(b + 8 * r)];
    fwd8(e, twld(twr,twi,128*u), twld(twr,twi,64*u), twld(twr,twi,32*u));
#pragma unroll
    for (int r = 0; r < 8; ++r) X[XS(b + 8 * r)] = e[r];
  }
  __syncthreads();
  {                                   // MS3: m=64, G=t>>6, u=t&63
    int u = t & 63, b = 512 * (t >> 6) + u;
    float2 e[8];
#pragma unroll
    for (int r = 0; r < 8; ++r) e[r] = X[XS(b + 64 * r)];
    fwd8(e, twld(twr,twi,16*u), twld(twr,twi,8*u), twld(twr,twi,4*u));
#pragma unroll
    for (int r = 0; r < 8; ++r) X[XS(b + 64 * r)] = e[r];
  }
  __syncthreads();
#pragma unroll
  for (int h = 0; h < 2; ++h) {       // MS4: radix-4, m=512
    int u = t + 256 * h;
    float2 f[4];
#pragma unroll
    for (int r = 0; r < 4; ++r) f[r] = X[XS(u + 512 * r)];
    float2 wA = twld(twr,twi,2*u), wB0 = twld(twr,twi,u), wB1 = mulmi(wB0);
    bfly(f[0], f[1], wA);  bfly(f[2], f[3], wA);
    bfly(f[0], f[2], wB0); bfly(f[1], f[3], wB1);
#pragma unroll
    for (int r = 0; r < 4; ++r) X[XS(u + 512 * r)] = f[r];
  }
  __syncthreads();
}

__device__ void fft_inv(float2* X, const float* twr, const float* twi, int t)
{
  const float2 one = mkf2(1.f, 0.f);
#pragma unroll
  for (int h = 0; h < 2; ++h) {       // MS4': radix-4, m=512
    int u = t + 256 * h;
    float2 f[4];
#pragma unroll
    for (int r = 0; r < 4; ++r) f[r] = X[XS(u + 512 * r)];
    float2 wA = twld(twr,twi,2*u), wB0 = twld(twr,twi,u), wB1 = mulmi(wB0);
    bflyc(f[0], f[2], wB0); bflyc(f[1], f[3], wB1);
    bflyc(f[0], f[1], wA);  bflyc(f[2], f[3], wA);
#pragma unroll
    for (int r = 0; r < 4; ++r) X[XS(u + 512 * r)] = f[r];
  }
  __syncthreads();
  {                                   // MS3'
    int u = t & 63, b = 512 * (t >> 6) + u;
    float2 e[8];
#pragma unroll
    for (int r = 0; r < 8; ++r) e[r] = X[XS(b + 64 * r)];
    inv8(e, twld(twr,twi,16*u), twld(twr,twi,8*u), twld(twr,twi,4*u));
#pragma unroll
    for (int r = 0; r < 8; ++r) X[XS(b + 64 * r)] = e[r];
  }
  __syncthreads();
  {                                   // MS2'
    int u = t >> 5, b = 64 * (t & 31) + u;
    float2 e[8];
#pragma unroll
    for (int r = 0; r < 8; ++r) e[r] = X[XS(b + 8 * r)];
    inv8(e, twld(twr,twi,128*u), twld(twr,twi,64*u), twld(twr,twi,32*u));
#pragma unroll
    for (int r = 0; r < 8; ++r) X[XS(b + 8 * r)] = e[r];
  }
  __syncthreads();
  {                                   // MS1'
    int b = 8 * t;
    float2 e[8];
#pragma unroll
    for (int r = 0; r < 8; ++r) e[r] = X[XS(b + r)];
    inv8(e, one, one, one);
#pragma unroll
    for (int r = 0; r < 8; ++r) X[XS(b + r)] = e[r];
  }
  __syncthreads();
}

// ------------------------------------------------------- twiddle table ----
__global__ __launch_bounds__(256)
void twiddle_init(float2* __restrict__ twg)
{
  int i = blockIdx.x * 256 + threadIdx.x;
  if (i < HALF_D) {
    float sv, cv;
    sincosf(-6.283185307179586f * (float)i / (float)D_DIM, &sv, &cv);
    twg[i] = mkf2(cv, sv);
  }
}

// ---------------------------------------------------------- FFT(k,v)·mul --
// One complex FFT of (k + i·v) recovers both real-input spectra.
// Writes packed half-spectrum of unit(Fk)·unit(Fv) over the k row.
__global__ __launch_bounds__(256)
void fftkv_kernel(float* __restrict__ kbuf, const unsigned short* __restrict__ vbuf,
                  const float2* __restrict__ twg)
{
  __shared__ float2 X[D_DIM];
  __shared__ float twr[HALF_D], twi[HALF_D];
  const int t = threadIdx.x;
  const size_t row = blockIdx.x;
  const float* krow = kbuf + row * D_DIM;
  const unsigned short* vrow = vbuf + row * D_DIM;

  for (int i = t; i < HALF_D; i += 256) {
    float2 w = twg[i]; int s = TS(i); twr[s] = w.x; twi[s] = w.y;
  }
  for (int i = t; i < D_DIM; i += 256) {
    int p = __brev((unsigned)i) >> 21;
    X[XS(p)] = mkf2(krow[i], bf2f(vrow[i]));
  }
  __syncthreads();
  fft_fwd(X, twr, twi, t);

  float2* outp = (float2*)(kbuf + row * D_DIM);
  for (int d = t; d < HALF_D; d += 256) {
    float2 p;
    if (d == 0) {
      float2 z0 = X[XS(0)], zn = X[XS(HALF_D)];
      float k0 = z0.x, v0 = z0.y, kn = zn.x, vn = zn.y;
      float p0 = (k0 / (fabsf(k0) + EPS_)) * (v0 / (fabsf(v0) + EPS_));
      float pn = (kn / (fabsf(kn) + EPS_)) * (vn / (fabsf(vn) + EPS_));
      p = mkf2(p0, pn);
    } else {
      float2 A = X[XS(d)];
      float2 Bc = X[XS(D_DIM - d)];
      float2 Bj = mkf2(Bc.x, -Bc.y);
      float2 Fk = mkf2(0.5f * (A.x + Bj.x), 0.5f * (A.y + Bj.y));
      float2 tt = mkf2(0.5f * (A.x - Bj.x), 0.5f * (A.y - Bj.y));
      float2 Fv = mkf2(tt.y, -tt.x);
      float sa = 1.f / (sqrtf(Fk.x*Fk.x + Fk.y*Fk.y) + EPS_);
      float sb = 1.f / (sqrtf(Fv.x*Fv.x + Fv.y*Fv.y) + EPS_);
      p = cmulf(Fk, Fv);
      float sc = sa * sb;
      p.x *= sc; p.y *= sc;
    }
    outp[d] = p;
  }
}

// --------------------------------------------------------------- scan -----
__global__ __launch_bounds__(256)
void scan_partial(const float2* __restrict__ kv, float2* __restrict__ part)
{
  int gid = blockIdx.x * 256 + threadIdx.x;
  int d = gid & (HALF_D - 1);
  int chunk = (gid >> 10) & (NCHUNK - 1);
  int b = gid >> 16;
  const float2* p = kv + ((size_t)(b * S_DIM + chunk * CHLEN) * HALF_D) + d;
  float2 acc = mkf2(0.f, 0.f);
  for (int s = 0; s < CHLEN; ++s) {
    float2 v = p[(size_t)s * HALF_D];
    acc.x += v.x; acc.y += v.y;
  }
  part[gid] = acc;
}

__global__ __launch_bounds__(256)
void scan_offsets(float2* __restrict__ part)
{
  int gid = blockIdx.x * 256 + threadIdx.x;
  int d = gid & (HALF_D - 1);
  int b = gid >> 10;
  float2* p = part + (size_t)b * (NCHUNK * HALF_D) + d;
  float2 acc = mkf2(0.f, 0.f);
  for (int c = 0; c < NCHUNK; ++c) {
    float2 v = p[(size_t)c * HALF_D];
    p[(size_t)c * HALF_D] = acc;
    acc.x += v.x; acc.y += v.y;
  }
}

__global__ __launch_bounds__(256)
void scan_apply(float2* __restrict__ kv, const float2* __restrict__ part)
{
  int gid = blockIdx.x * 256 + threadIdx.x;
  int d = gid & (HALF_D - 1);
  int chunk = (gid >> 10) & (NCHUNK - 1);
  int b = gid >> 16;
  float2* p = kv + ((size_t)(b * S_DIM + chunk * CHLEN) * HALF_D) + d;
  float2 acc = part[gid];
  for (int s = 0; s < CHLEN; ++s) {
    float2 v = p[(size_t)s * HALF_D];
    acc.x += v.x; acc.y += v.y;
    p[(size_t)s * HALF_D] = acc;
  }
}

// --------------------------------------------------------------- final ----
// out = base + gate * real(ifft(conj(Fq) * Fmem)), FFT(q) in place, G in
// place, DIF inverse (bit-reversed output absorbed in gather).
__global__ __launch_bounds__(256)
void final_kernel(float* __restrict__ qo, const float2* __restrict__ mem,
                  const float* __restrict__ base, const float* __restrict__ gate,
                  const float2* __restrict__ twg)
{
  __shared__ float2 X[D_DIM];
  __shared__ float twr[HALF_D], twi[HALF_D];
  const int t = threadIdx.x;
  const size_t row = blockIdx.x;
  float* qrow = qo + row * D_DIM;
  const float2* mrow = mem + row * HALF_D;

  for (int i = t; i < HALF_D; i += 256) {
    float2 w = twg[i]; int s = TS(i); twr[s] = w.x; twi[s] = w.y;
  }
  for (int i = t; i < D_DIM; i += 256) {
    int p = __brev((unsigned)i) >> 21;
    X[XS(p)] = mkf2(qrow[i], 0.f);
  }
  __syncthreads();
  fft_fwd(X, twr, twi, t);

  // G = conj(Fq) * Fmem, in place (thread owns the (d, 2048-d) pair)
  for (int d = t; d < HALF_D; d += 256) {
    if (d == 0) {
      float2 fm = mrow[0];                       // (P0, P1024), both real
      float2 f0 = X[XS(0)], f1 = X[XS(HALF_D)];
      X[XS(0)]      = mkf2(f0.x * fm.x, -f0.y * fm.x);
      X[XS(HALF_D)] = mkf2(f1.x * fm.y, -f1.y * fm.y);
    } else {
      float2 fm = mrow[d];
      float2 fq = X[XS(d)];
      X[XS(d)] = mkf2(fq.x*fm.x + fq.y*fm.y, fq.x*fm.y - fq.y*fm.x);       // conj(fq)*fm
      float2 f2 = X[XS(D_DIM - d)];
      X[XS(D_DIM - d)] = mkf2(f2.x*fm.x - f2.y*fm.y, -f2.x*fm.y - f2.y*fm.x); // conj(f2)*conj(fm)
    }
  }
  __syncthreads();
  fft_inv(X, twr, twi, t);

  const float gv = gate[0] * (1.f / (float)D_DIM);
  const float* brow = base + row * D_DIM;
  for (int i = t; i < D_DIM; i += 256) {
    int p = __brev((unsigned)i) >> 21;           // time sample i lives at brev(i)
    qrow[i] = brow[i] + gv * X[XS(p)].x;
  }
}

// ------------------------------------------------------------ launcher ----
extern "C" void kernel_launch(void* const* d_in, const int* in_sizes, int n_in,
                              void* d_out, int out_size, void* d_ws, size_t ws_size,
                              hipStream_t stream)
{
  const float* hs   = (const float*)d_in[0];
  const float* base = (const float*)d_in[1];
  const float* Wq   = (const float*)d_in[2];
  const float* bq   = (const float*)d_in[3];
  const float* Wk   = (const float*)d_in[4];
  const float* bk   = (const float*)d_in[5];
  const float* Wv   = (const float*)d_in[6];
  const float* bv   = (const float*)d_in[7];
  const float* gate = (const float*)d_in[8];
  float* out  = (float*)d_out;

  // workspace layout (160.4 MB):
  //   hsb  bf16 [8192][2048]   (first 8KB reused as twiddle table post-GEMM)
  //   wqb/wkb/wvb bf16 [2048][2048] x3
  //   kbuf f32  [8192][2048] (→ packed Fkv / Fmem)
  //   vbuf bf16 [8192][2048]
  //   part f32x2 [2][64][1024]
  char* ws = (char*)d_ws;
  unsigned short* hsb = (unsigned short*)ws;
  unsigned short* wqb = (unsigned short*)(ws + 33554432);
  unsigned short* wkb = wqb + (size_t)D_DIM * D_DIM;
  unsigned short* wvb = wkb + (size_t)D_DIM * D_DIM;
  float*  kbuf = (float*)(ws + 58720256);
  unsigned short* vbuf = (unsigned short*)(ws + 58720256 + 67108864);
  float2* part = (float2*)(ws + 58720256 + 67108864 + 33554432);
  float2* twg  = (float2*)ws;   // overwrites hsb AFTER the GEMMs consumed it

  {
    int n8 = (NROW * D_DIM) / 8;
    cvt_f32_bf16<<<n8 / 256, 256, 0, stream>>>(hs, hsb, n8);
    int w8 = (D_DIM * D_DIM) / 8;
    cvt_f32_bf16<<<w8 / 256, 256, 0, stream>>>(Wq, wqb, w8);
    cvt_f32_bf16<<<w8 / 256, 256, 0, stream>>>(Wk, wkb, w8);
    cvt_f32_bf16<<<w8 / 256, 256, 0, stream>>>(Wv, wvb, w8);
  }

  dim3 gg(NROW / 128, D_DIM / 128);
  gemm_mfma_bf16<0><<<gg, 256, 0, stream>>>(hsb, wqb, bq, out,  NROW, D_DIM, D_DIM);
  gemm_mfma_bf16<0><<<gg, 256, 0, stream>>>(hsb, wkb, bk, kbuf, NROW, D_DIM, D_DIM);
  gemm_mfma_bf16<1><<<gg, 256, 0, stream>>>(hsb, wvb, bv, vbuf, NROW, D_DIM, D_DIM);

  twiddle_init<<<4, 256, 0, stream>>>(twg);    // after GEMMs (reuses hsb space)

  fftkv_kernel<<<NROW, 256, 0, stream>>>(kbuf, vbuf, twg);

  scan_partial<<<(B_DIM * NCHUNK * HALF_D) / 256, 256, 0, stream>>>(
      (const float2*)kbuf, part);
  scan_offsets<<<(B_DIM * HALF_D) / 256, 256, 0, stream>>>(part);
  scan_apply<<<(B_DIM * NCHUNK * HALF_D) / 256, 256, 0, stream>>>(
      (float2*)kbuf, part);

  final_kernel<<<NROW, 256, 0, stream>>>(out, (const float2*)kbuf, base, gate, twg);
}

// Round 4
// 438.320 us; speedup vs baseline: 6.8989x; 1.2436x over previous
//
#include <hip/hip_runtime.h>
#include <math.h>

constexpr int D_DIM  = 2048;   // feature dim (FFT length)
constexpr int HALF_D = 1024;
constexpr int B_DIM  = 2;
constexpr int S_DIM  = 4096;
constexpr int NROW   = B_DIM * S_DIM;      // 8192
constexpr int NCHUNK = 64;                 // scan chunks along S
constexpr int CHLEN  = S_DIM / NCHUNK;     // 64
constexpr float EPS_ = 1e-8f;

typedef __attribute__((ext_vector_type(8))) short  short8;   // bf16x8 frag
typedef __attribute__((ext_vector_type(8))) unsigned short ushort8;
typedef __attribute__((ext_vector_type(4))) float  f32x4;    // MFMA acc

__device__ __forceinline__ float2 mkf2(float x, float y){ float2 r; r.x=x; r.y=y; return r; }
__device__ __forceinline__ float2 cmulf(float2 a, float2 b){
  return mkf2(fmaf(a.x, b.x, -a.y*b.y), fmaf(a.x, b.y, a.y*b.x));
}
__device__ __forceinline__ unsigned short f2bf(float x){
  unsigned u = __float_as_uint(x);
  u += 0x7fff + ((u >> 16) & 1);           // round-to-nearest-even
  return (unsigned short)(u >> 16);
}
__device__ __forceinline__ float bf2f(unsigned short h){
  return __uint_as_float(((unsigned)h) << 16);
}

// ------------------------------------------------------------ fp32→bf16 ---
__global__ __launch_bounds__(256)
void cvt_f32_bf16(const float* __restrict__ in, unsigned short* __restrict__ out, int n8)
{
  int i = blockIdx.x * 256 + threadIdx.x;
  if (i >= n8) return;
  const float4* p = (const float4*)in + (size_t)i * 2;
  float4 a = p[0], b = p[1];
  ushort8 o;
  o[0]=f2bf(a.x); o[1]=f2bf(a.y); o[2]=f2bf(a.z); o[3]=f2bf(a.w);
  o[4]=f2bf(b.x); o[5]=f2bf(b.y); o[6]=f2bf(b.z); o[7]=f2bf(b.w);
  *(ushort8*)(out + (size_t)i * 8) = o;
}

// ------------------------- fused q/k/v 256x256 MFMA GEMM (tri-buffered) ---
// A [8192][2048] bf16, Wc [6144][2048] bf16 (Wq|Wk|Wv rows concatenated).
// C = A @ Wc^T + bias; block col-range selects dest: q->f32, k->f32, v->bf16.
// 8 waves (2Mx4N), per-wave 128x64 output, BK=32, tri-buffer LDS, staging
// 2 K-tiles ahead, counted s_waitcnt vmcnt(4) (never 0 in loop), raw
// s_barrier, setprio around MFMA clusters, XOR-swizzled LDS (2-way reads).
__global__ __launch_bounds__(512, 2)
void gemm_fused(const unsigned short* __restrict__ A,
                const unsigned short* __restrict__ Wc,
                const float* __restrict__ bq, const float* __restrict__ bk,
                const float* __restrict__ bv,
                float* __restrict__ qout, float* __restrict__ kout,
                unsigned short* __restrict__ vout)
{
  constexpr int K = 2048, NT = K / 32;            // 64 K-tiles
  __shared__ unsigned short lds[49152];           // 96 KB = A[3][8192] + B[3][8192]
  const int tid  = threadIdx.x;
  const int wid  = tid >> 6, lane = tid & 63;
  const int wr   = wid >> 2, wc = wid & 3;

  // XCD-bijective swizzle: 768 blocks, 96 per XCD chunk; chunk = 4 M x 24 N
  int bid = blockIdx.x;
  int sw  = (bid & 7) * 96 + (bid >> 3);
  const int bm = (sw / 24) * 256, bn = (sw % 24) * 256;

  // staging source (per lane): slot s = r*512+tid -> row tid>>2 (+r*128),
  // stored chunk c'=tid&3 holds k-chunk c' ^ ((row>>1)&3)
  const int srow = tid >> 2;
  const int skc  = ((tid & 3) ^ ((tid >> 3) & 3)) * 8;
  const unsigned short* Ag = A  + (size_t)(bm + srow) * K + skc;
  const unsigned short* Bg = Wc + (size_t)(bn + srow) * K + skc;

  unsigned short* Abase = lds;
  unsigned short* Bbase = lds + 24576;
  const int stoff = wid * 512;                    // wave-uniform dest (r=0)

  // fragment read offsets (ushort units); row stride 32, swizzled chunk
  const int fr  = lane & 15;
  const int sig = ((lane >> 4) ^ ((lane >> 1) & 3)) * 8;
  const int aro = (wr * 128 + fr) * 32 + sig;     // + qm*2048 + i*512
  const int bro = (wc * 64 + fr) * 32 + sig;      // + j*512

  auto stA = [&](int kt, int b, int r) {
    __builtin_amdgcn_global_load_lds(
      (const __attribute__((address_space(1))) void*)(Ag + (size_t)r * 128 * K + kt * 32),
      (__attribute__((address_space(3))) void*)(Abase + b * 8192 + r * 4096 + stoff),
      16, 0, 0);
  };
  auto stB = [&](int kt, int b, int r) {
    __builtin_amdgcn_global_load_lds(
      (const __attribute__((address_space(1))) void*)(Bg + (size_t)r * 128 * K + kt * 32),
      (__attribute__((address_space(3))) void*)(Bbase + b * 8192 + r * 4096 + stoff),
      16, 0, 0);
  };

  f32x4 acc[8][4];
#pragma unroll
  for (int i = 0; i < 8; ++i)
#pragma unroll
    for (int j = 0; j < 4; ++j) acc[i][j] = (f32x4){0.f, 0.f, 0.f, 0.f};

  // prologue: tile0 -> buf0, tile1 -> buf1; wait tile0 (4 newest remain)
  stA(0, 0, 0); stA(0, 0, 1); stB(0, 0, 0); stB(0, 0, 1);
  stA(1, 1, 0); stA(1, 1, 1); stB(1, 1, 0); stB(1, 1, 1);
  asm volatile("s_waitcnt vmcnt(4)" ::: "memory");
  __builtin_amdgcn_s_barrier();
  __builtin_amdgcn_sched_barrier(0);

  int c = 0;
#pragma unroll 1
  for (int kt = 0; kt < NT; ++kt) {
    const unsigned short* Ab = Abase + c * 8192;
    const unsigned short* Bb = Bbase + c * 8192;
    int nb = c + 2; if (nb >= 3) nb -= 3;

    // ---- phase A: stage A(kt+2) | read qm=0 frags + B frags | 16 MFMA
    if (kt < NT - 2) { stA(kt + 2, nb, 0); stA(kt + 2, nb, 1); }
    short8 af0[4], bfr[4];
#pragma unroll
    for (int i = 0; i < 4; ++i) af0[i] = *(const short8*)(Ab + aro + i * 512);
#pragma unroll
    for (int j = 0; j < 4; ++j) bfr[j] = *(const short8*)(Bb + bro + j * 512);
    __builtin_amdgcn_s_setprio(1);
#pragma unroll
    for (int i = 0; i < 4; ++i)
#pragma unroll
      for (int j = 0; j < 4; ++j)
        acc[i][j] = __builtin_amdgcn_mfma_f32_16x16x32_bf16(af0[i], bfr[j], acc[i][j], 0, 0, 0);
    __builtin_amdgcn_s_setprio(0);

    // ---- phase B: stage B(kt+2) | read qm=1 frags | 16 MFMA (reuse bfr)
    if (kt < NT - 2) { stB(kt + 2, nb, 0); stB(kt + 2, nb, 1); }
    short8 af1[4];
#pragma unroll
    for (int i = 0; i < 4; ++i) af1[i] = *(const short8*)(Ab + aro + 2048 + i * 512);
    __builtin_amdgcn_s_setprio(1);
#pragma unroll
    for (int i = 0; i < 4; ++i)
#pragma unroll
      for (int j = 0; j < 4; ++j)
        acc[4 + i][j] = __builtin_amdgcn_mfma_f32_16x16x32_bf16(af1[i], bfr[j], acc[4 + i][j], 0, 0, 0);
    __builtin_amdgcn_s_setprio(0);

    // ---- tile boundary: counted wait + raw barrier
    if (kt < NT - 1) {
      if (kt < NT - 2) asm volatile("s_waitcnt vmcnt(4)" ::: "memory");
      else             asm volatile("s_waitcnt vmcnt(0)" ::: "memory");
      __builtin_amdgcn_s_barrier();
      __builtin_amdgcn_sched_barrier(0);
    }
    c = (c == 2) ? 0 : c + 1;
  }

  // ---- epilogue: route by segment (q/k f32, v bf16), add bias
  const int seg = bn >> 11;                        // 0:q 1:k 2:v
  const float* bp = (seg == 0) ? bq : (seg == 1) ? bk : bv;
  float bias_j[4];
#pragma unroll
  for (int j = 0; j < 4; ++j)
    bias_j[j] = bp[(bn + wc * 64 + j * 16 + fr) & 2047];
  const int er = (lane >> 4) * 4;
#pragma unroll
  for (int I = 0; I < 8; ++I) {
    int row = bm + wr * 128 + (I >> 2) * 64 + (I & 3) * 16 + er;
#pragma unroll
    for (int j = 0; j < 4; ++j) {
      int col = (bn + wc * 64 + j * 16 + fr) & 2047;
#pragma unroll
      for (int r = 0; r < 4; ++r) {
        float val = acc[I][j][r] + bias_j[j];
        if (seg == 2)
          vout[(size_t)(row + r) * 2048 + col] = f2bf(val);
        else if (seg == 1)
          kout[(size_t)(row + r) * 2048 + col] = val;
        else
          qout[(size_t)(row + r) * 2048 + col] = val;
      }
    }
  }
}

// ------------------------------------------------------------- FFT core ---
// 2048-pt FFT, 256 threads, radix 8-8-8-4 macro-stages, register butterflies.
__device__ __forceinline__ int XS(int i){ return i ^ (((i >> 5) ^ (i >> 10)) & 31); }
__device__ __forceinline__ int TS(int i){ return i ^ ((i >> 5) & 31); }

__device__ __forceinline__ float2 mulmi(float2 w){ return mkf2(w.y, -w.x); }   // w * (-i)
__device__ __forceinline__ float2 mulw8(float2 w){                              // w * e^{-i pi/4}
  const float c = 0.70710678118654752f;
  return mkf2(c * (w.x + w.y), c * (w.y - w.x));
}
__device__ __forceinline__ void bfly(float2& a, float2& b, float2 w){
  float2 v = cmulf(w, b);
  b = mkf2(a.x - v.x, a.y - v.y);
  a = mkf2(a.x + v.x, a.y + v.y);
}
__device__ __forceinline__ void bflyc(float2& a, float2& b, float2 w){
  float2 d = mkf2(a.x - b.x, a.y - b.y);
  a = mkf2(a.x + b.x, a.y + b.y);
  b = mkf2(fmaf(d.x, w.x, d.y * w.y), fmaf(d.y, w.x, -d.x * w.y));  // d * conj(w)
}

__device__ __forceinline__ void fwd8(float2 e[8], float2 wA, float2 wB0, float2 wC0){
  bfly(e[0], e[1], wA); bfly(e[2], e[3], wA); bfly(e[4], e[5], wA); bfly(e[6], e[7], wA);
  float2 wB1 = mulmi(wB0);
  bfly(e[0], e[2], wB0); bfly(e[1], e[3], wB1); bfly(e[4], e[6], wB0); bfly(e[5], e[7], wB1);
  float2 wC1 = mulw8(wC0), wC2 = mulmi(wC0), wC3 = mulmi(wC1);
  bfly(e[0], e[4], wC0); bfly(e[1], e[5], wC1); bfly(e[2], e[6], wC2); bfly(e[3], e[7], wC3);
}
__device__ __forceinline__ void inv8(float2 e[8], float2 wA, float2 wB0, float2 wC0){
  float2 wC1 = mulw8(wC0), wC2 = mulmi(wC0), wC3 = mulmi(wC1);
  bflyc(e[0], e[4], wC0); bflyc(e[1], e[5], wC1); bflyc(e[2], e[6], wC2); bflyc(e[3], e[7], wC3);
  float2 wB1 = mulmi(wB0);
  bflyc(e[0], e[2], wB0); bflyc(e[1], e[3], wB1); bflyc(e[4], e[6], wB0); bflyc(e[5], e[7], wB1);
  bflyc(e[0], e[1], wA); bflyc(e[2], e[3], wA); bflyc(e[4], e[5], wA); bflyc(e[6], e[7], wA);
}

__device__ __forceinline__ float2 twld(const float* twr, const float* twi, int i){
  int s = TS(i);
  return mkf2(twr[s], twi[s]);
}

__device__ void fft_fwd(float2* X, const float* twr, const float* twi, int t)
{
  const float2 one = mkf2(1.f, 0.f);
  {                                   // MS1
    int b = 8 * t;
    float2 e[8];
#pragma unroll
    for (int r = 0; r < 8; ++r) e[r] = X[XS(b + r)];
    fwd8(e, one, one, one);
#pragma unroll
    for (int r = 0; r < 8; ++r) X[XS(b + r)] = e[r];
  }
  __syncthreads();
  {                                   // MS2
    int u = t >> 5, b = 64 * (t & 31) + u;
    float2 e[8];
#pragma unroll
    for (int r = 0; r < 8; ++r) e[r] = X[XS(b + 8 * r)];
    fwd8(e, twld(twr,twi,128*u), twld(twr,twi,64*u), twld(twr,twi,32*u));
#pragma unroll
    for (int r = 0; r < 8; ++r) X[XS(b + 8 * r)] = e[r];
  }
  __syncthreads();
  {                                   // MS3
    int u = t & 63, b = 512 * (t >> 6) + u;
    float2 e[8];
#pragma unroll
    for (int r = 0; r < 8; ++r) e[r] = X[XS(b + 64 * r)];
    fwd8(e, twld(twr,twi,16*u), twld(twr,twi,8*u), twld(twr,twi,4*u));
#pragma unroll
    for (int r = 0; r < 8; ++r) X[XS(b + 64 * r)] = e[r];
  }
  __syncthreads();
#pragma unroll
  for (int h = 0; h < 2; ++h) {       // MS4: radix-4
    int u = t + 256 * h;
    float2 f[4];
#pragma unroll
    for (int r = 0; r < 4; ++r) f[r] = X[XS(u + 512 * r)];
    float2 wA = twld(twr,twi,2*u), wB0 = twld(twr,twi,u), wB1 = mulmi(wB0);
    bfly(f[0], f[1], wA);  bfly(f[2], f[3], wA);
    bfly(f[0], f[2], wB0); bfly(f[1], f[3], wB1);
#pragma unroll
    for (int r = 0; r < 4; ++r) X[XS(u + 512 * r)] = f[r];
  }
  __syncthreads();
}

__device__ void fft_inv(float2* X, const float* twr, const float* twi, int t)
{
  const float2 one = mkf2(1.f, 0.f);
#pragma unroll
  for (int h = 0; h < 2; ++h) {       // MS4'
    int u = t + 256 * h;
    float2 f[4];
#pragma unroll
    for (int r = 0; r < 4; ++r) f[r] = X[XS(u + 512 * r)];
    float2 wA = twld(twr,twi,2*u), wB0 = twld(twr,twi,u), wB1 = mulmi(wB0);
    bflyc(f[0], f[2], wB0); bflyc(f[1], f[3], wB1);
    bflyc(f[0], f[1], wA);  bflyc(f[2], f[3], wA);
#pragma unroll
    for (int r = 0; r < 4; ++r) X[XS(u + 512 * r)] = f[r];
  }
  __syncthreads();
  {                                   // MS3'
    int u = t & 63, b = 512 * (t >> 6) + u;
    float2 e[8];
#pragma unroll
    for (int r = 0; r < 8; ++r) e[r] = X[XS(b + 64 * r)];
    inv8(e, twld(twr,twi,16*u), twld(twr,twi,8*u), twld(twr,twi,4*u));
#pragma unroll
    for (int r = 0; r < 8; ++r) X[XS(b + 64 * r)] = e[r];
  }
  __syncthreads();
  {                                   // MS2'
    int u = t >> 5, b = 64 * (t & 31) + u;
    float2 e[8];
#pragma unroll
    for (int r = 0; r < 8; ++r) e[r] = X[XS(b + 8 * r)];
    inv8(e, twld(twr,twi,128*u), twld(twr,twi,64*u), twld(twr,twi,32*u));
#pragma unroll
    for (int r = 0; r < 8; ++r) X[XS(b + 8 * r)] = e[r];
  }
  __syncthreads();
  {                                   // MS1'
    int b = 8 * t;
    float2 e[8];
#pragma unroll
    for (int r = 0; r < 8; ++r) e[r] = X[XS(b + r)];
    inv8(e, one, one, one);
#pragma unroll
    for (int r = 0; r < 8; ++r) X[XS(b + r)] = e[r];
  }
  __syncthreads();
}

// ------------------------------------------------------- twiddle table ----
__global__ __launch_bounds__(256)
void twiddle_init(float2* __restrict__ twg)
{
  int i = blockIdx.x * 256 + threadIdx.x;
  if (i < HALF_D) {
    float sv, cv;
    sincosf(-6.283185307179586f * (float)i / (float)D_DIM, &sv, &cv);
    twg[i] = mkf2(cv, sv);
  }
}

// ---------------------------------------------------------- FFT(k,v)·mul --
__global__ __launch_bounds__(256)
void fftkv_kernel(float* __restrict__ kbuf, const unsigned short* __restrict__ vbuf,
                  const float2* __restrict__ twg)
{
  __shared__ float2 X[D_DIM];
  __shared__ float twr[HALF_D], twi[HALF_D];
  const int t = threadIdx.x;
  const size_t row = blockIdx.x;
  const float* krow = kbuf + row * D_DIM;
  const unsigned short* vrow = vbuf + row * D_DIM;

  for (int i = t; i < HALF_D; i += 256) {
    float2 w = twg[i]; int s = TS(i); twr[s] = w.x; twi[s] = w.y;
  }
  for (int i = t; i < D_DIM; i += 256) {
    int p = __brev((unsigned)i) >> 21;
    X[XS(p)] = mkf2(krow[i], bf2f(vrow[i]));
  }
  __syncthreads();
  fft_fwd(X, twr, twi, t);

  float2* outp = (float2*)(kbuf + row * D_DIM);
  for (int d = t; d < HALF_D; d += 256) {
    float2 p;
    if (d == 0) {
      float2 z0 = X[XS(0)], zn = X[XS(HALF_D)];
      float k0 = z0.x, v0 = z0.y, kn = zn.x, vn = zn.y;
      float p0 = (k0 / (fabsf(k0) + EPS_)) * (v0 / (fabsf(v0) + EPS_));
      float pn = (kn / (fabsf(kn) + EPS_)) * (vn / (fabsf(vn) + EPS_));
      p = mkf2(p0, pn);
    } else {
      float2 A = X[XS(d)];
      float2 Bc = X[XS(D_DIM - d)];
      float2 Bj = mkf2(Bc.x, -Bc.y);
      float2 Fk = mkf2(0.5f * (A.x + Bj.x), 0.5f * (A.y + Bj.y));
      float2 tt = mkf2(0.5f * (A.x - Bj.x), 0.5f * (A.y - Bj.y));
      float2 Fv = mkf2(tt.y, -tt.x);
      float sa = 1.f / (sqrtf(Fk.x*Fk.x + Fk.y*Fk.y) + EPS_);
      float sb = 1.f / (sqrtf(Fv.x*Fv.x + Fv.y*Fv.y) + EPS_);
      p = cmulf(Fk, Fv);
      float sc = sa * sb;
      p.x *= sc; p.y *= sc;
    }
    outp[d] = p;
  }
}

// --------------------------------------------------------------- scan -----
__global__ __launch_bounds__(256)
void scan_partial(const float2* __restrict__ kv, float2* __restrict__ part)
{
  int gid = blockIdx.x * 256 + threadIdx.x;
  int d = gid & (HALF_D - 1);
  int chunk = (gid >> 10) & (NCHUNK - 1);
  int b = gid >> 16;
  const float2* p = kv + ((size_t)(b * S_DIM + chunk * CHLEN) * HALF_D) + d;
  float2 acc = mkf2(0.f, 0.f);
  for (int s = 0; s < CHLEN; ++s) {
    float2 v = p[(size_t)s * HALF_D];
    acc.x += v.x; acc.y += v.y;
  }
  part[gid] = acc;
}

__global__ __launch_bounds__(256)
void scan_offsets(float2* __restrict__ part)
{
  int gid = blockIdx.x * 256 + threadIdx.x;
  int d = gid & (HALF_D - 1);
  int b = gid >> 10;
  float2* p = part + (size_t)b * (NCHUNK * HALF_D) + d;
  float2 acc = mkf2(0.f, 0.f);
  for (int c = 0; c < NCHUNK; ++c) {
    float2 v = p[(size_t)c * HALF_D];
    p[(size_t)c * HALF_D] = acc;
    acc.x += v.x; acc.y += v.y;
  }
}

__global__ __launch_bounds__(256)
void scan_apply(float2* __restrict__ kv, const float2* __restrict__ part)
{
  int gid = blockIdx.x * 256 + threadIdx.x;
  int d = gid & (HALF_D - 1);
  int chunk = (gid >> 10) & (NCHUNK - 1);
  int b = gid >> 16;
  float2* p = kv + ((size_t)(b * S_DIM + chunk * CHLEN) * HALF_D) + d;
  float2 acc = part[gid];
  for (int s = 0; s < CHLEN; ++s) {
    float2 v = p[(size_t)s * HALF_D];
    acc.x += v.x; acc.y += v.y;
    p[(size_t)s * HALF_D] = acc;
  }
}

// --------------------------------------------------------------- final ----
__global__ __launch_bounds__(256)
void final_kernel(float* __restrict__ qo, const float2* __restrict__ mem,
                  const float* __restrict__ base, const float* __restrict__ gate,
                  const float2* __restrict__ twg)
{
  __shared__ float2 X[D_DIM];
  __shared__ float twr[HALF_D], twi[HALF_D];
  const int t = threadIdx.x;
  const size_t row = blockIdx.x;
  float* qrow = qo + row * D_DIM;
  const float2* mrow = mem + row * HALF_D;

  for (int i = t; i < HALF_D; i += 256) {
    float2 w = twg[i]; int s = TS(i); twr[s] = w.x; twi[s] = w.y;
  }
  for (int i = t; i < D_DIM; i += 256) {
    int p = __brev((unsigned)i) >> 21;
    X[XS(p)] = mkf2(qrow[i], 0.f);
  }
  __syncthreads();
  fft_fwd(X, twr, twi, t);

  for (int d = t; d < HALF_D; d += 256) {
    if (d == 0) {
      float2 fm = mrow[0];
      float2 f0 = X[XS(0)], f1 = X[XS(HALF_D)];
      X[XS(0)]      = mkf2(f0.x * fm.x, -f0.y * fm.x);
      X[XS(HALF_D)] = mkf2(f1.x * fm.y, -f1.y * fm.y);
    } else {
      float2 fm = mrow[d];
      float2 fq = X[XS(d)];
      X[XS(d)] = mkf2(fq.x*fm.x + fq.y*fm.y, fq.x*fm.y - fq.y*fm.x);
      float2 f2 = X[XS(D_DIM - d)];
      X[XS(D_DIM - d)] = mkf2(f2.x*fm.x - f2.y*fm.y, -f2.x*fm.y - f2.y*fm.x);
    }
  }
  __syncthreads();
  fft_inv(X, twr, twi, t);

  const float gv = gate[0] * (1.f / (float)D_DIM);
  const float* brow = base + row * D_DIM;
  for (int i = t; i < D_DIM; i += 256) {
    int p = __brev((unsigned)i) >> 21;
    qrow[i] = brow[i] + gv * X[XS(p)].x;
  }
}

// ------------------------------------------------------------ launcher ----
extern "C" void kernel_launch(void* const* d_in, const int* in_sizes, int n_in,
                              void* d_out, int out_size, void* d_ws, size_t ws_size,
                              hipStream_t stream)
{
  const float* hs   = (const float*)d_in[0];
  const float* base = (const float*)d_in[1];
  const float* Wq   = (const float*)d_in[2];
  const float* bq   = (const float*)d_in[3];
  const float* Wk   = (const float*)d_in[4];
  const float* bk   = (const float*)d_in[5];
  const float* Wv   = (const float*)d_in[6];
  const float* bv   = (const float*)d_in[7];
  const float* gate = (const float*)d_in[8];
  float* out  = (float*)d_out;

  // workspace layout (160.4 MB):
  //   hsb  bf16 [8192][2048]   (first 8KB reused as twiddle table post-GEMM)
  //   wqb|wkb|wvb bf16 [6144][2048] contiguous (fused weight)
  //   kbuf f32  [8192][2048] (→ packed Fkv / Fmem)
  //   vbuf bf16 [8192][2048]
  //   part f32x2 [2][64][1024]
  char* ws = (char*)d_ws;
  unsigned short* hsb = (unsigned short*)ws;
  unsigned short* wqb = (unsigned short*)(ws + 33554432);
  unsigned short* wkb = wqb + (size_t)D_DIM * D_DIM;
  unsigned short* wvb = wkb + (size_t)D_DIM * D_DIM;
  float*  kbuf = (float*)(ws + 58720256);
  unsigned short* vbuf = (unsigned short*)(ws + 58720256 + 67108864);
  float2* part = (float2*)(ws + 58720256 + 67108864 + 33554432);
  float2* twg  = (float2*)ws;   // overwrites hsb AFTER the GEMM consumed it

  {
    int n8 = (NROW * D_DIM) / 8;
    cvt_f32_bf16<<<n8 / 256, 256, 0, stream>>>(hs, hsb, n8);
    int w8 = (D_DIM * D_DIM) / 8;
    cvt_f32_bf16<<<w8 / 256, 256, 0, stream>>>(Wq, wqb, w8);
    cvt_f32_bf16<<<w8 / 256, 256, 0, stream>>>(Wk, wkb, w8);
    cvt_f32_bf16<<<w8 / 256, 256, 0, stream>>>(Wv, wvb, w8);
  }

  gemm_fused<<<768, 512, 0, stream>>>(hsb, wqb, bq, bk, bv, out, kbuf, vbuf);

  twiddle_init<<<4, 256, 0, stream>>>(twg);

  fftkv_kernel<<<NROW, 256, 0, stream>>>(kbuf, vbuf, twg);

  scan_partial<<<(B_DIM * NCHUNK * HALF_D) / 256, 256, 0, stream>>>(
      (const float2*)kbuf, part);
  scan_offsets<<<(B_DIM * HALF_D) / 256, 256, 0, stream>>>(part);
  scan_apply<<<(B_DIM * NCHUNK * HALF_D) / 256, 256, 0, stream>>>(
      (float2*)kbuf, part);

  final_kernel<<<NROW, 256, 0, stream>>>(out, (const float2*)kbuf, base, gate, twg);
}

// Round 5
// 433.331 us; speedup vs baseline: 6.9783x; 1.0115x over previous
//
#include <hip/hip_runtime.h>
#include <math.h>

constexpr int D_DIM  = 2048;   // feature dim (FFT length)
constexpr int HALF_D = 1024;
constexpr int B_DIM  = 2;
constexpr int S_DIM  = 4096;
constexpr int NROW   = B_DIM * S_DIM;      // 8192
constexpr int NCHUNK = 64;                 // scan chunks along S
constexpr int CHLEN  = S_DIM / NCHUNK;     // 64
constexpr float EPS_ = 1e-8f;

typedef __attribute__((ext_vector_type(8))) short  short8;   // bf16x8 frag
typedef __attribute__((ext_vector_type(8))) unsigned short ushort8;
typedef __attribute__((ext_vector_type(4))) float  f32x4;    // MFMA acc

__device__ __forceinline__ float2 mkf2(float x, float y){ float2 r; r.x=x; r.y=y; return r; }
__device__ __forceinline__ float2 cmulf(float2 a, float2 b){
  return mkf2(fmaf(a.x, b.x, -a.y*b.y), fmaf(a.x, b.y, a.y*b.x));
}
__device__ __forceinline__ unsigned short f2bf(float x){
  unsigned u = __float_as_uint(x);
  u += 0x7fff + ((u >> 16) & 1);           // round-to-nearest-even
  return (unsigned short)(u >> 16);
}
__device__ __forceinline__ float bf2f(unsigned short h){
  return __uint_as_float(((unsigned)h) << 16);
}

// ------------------------------------------------------------ fp32→bf16 ---
__global__ __launch_bounds__(256)
void cvt_f32_bf16(const float* __restrict__ in, unsigned short* __restrict__ out, int n8)
{
  int i = blockIdx.x * 256 + threadIdx.x;
  if (i >= n8) return;
  const float4* p = (const float4*)in + (size_t)i * 2;
  float4 a = p[0], b = p[1];
  ushort8 o;
  o[0]=f2bf(a.x); o[1]=f2bf(a.y); o[2]=f2bf(a.z); o[3]=f2bf(a.w);
  o[4]=f2bf(b.x); o[5]=f2bf(b.y); o[6]=f2bf(b.z); o[7]=f2bf(b.w);
  *(ushort8*)(out + (size_t)i * 8) = o;
}

// ------------------------- fused q/k/v 256x256 MFMA GEMM (tri-buffered) ---
// A [8192][2048] bf16, Wc [6144][2048] bf16 (Wq|Wk|Wv rows concatenated).
// C = A @ Wc^T + bias; q -> f32 (d_out), k/v -> bf16 interleaved kvb rows.
// 8 waves (2Mx4N), per-wave 128x64 output, BK=32, tri-buffer LDS, staging
// 2 K-tiles ahead, counted s_waitcnt vmcnt(4), per-phase barrier pairs,
// setprio around MFMA clusters, XOR-swizzled LDS (2-way reads, conflict-free).
__global__ __launch_bounds__(512, 2)
void gemm_fused(const unsigned short* __restrict__ A,
                const unsigned short* __restrict__ Wc,
                const float* __restrict__ bq, const float* __restrict__ bk,
                const float* __restrict__ bv,
                float* __restrict__ qout, unsigned short* __restrict__ kvb)
{
  constexpr int K = 2048, NT = K / 32;            // 64 K-tiles
  __shared__ unsigned short lds[49152];           // 96 KB = A[3][8192] + B[3][8192]
  const int tid  = threadIdx.x;
  const int wid  = tid >> 6, lane = tid & 63;
  const int wr   = wid >> 2, wc = wid & 3;

  // XCD-bijective swizzle: 768 blocks, 96 per XCD chunk; chunk = 4 M x 24 N
  int bid = blockIdx.x;
  int sw  = (bid & 7) * 96 + (bid >> 3);
  const int bm = (sw / 24) * 256, bn = (sw % 24) * 256;

  const int srow = tid >> 2;
  const int skc  = ((tid & 3) ^ ((tid >> 3) & 3)) * 8;
  const unsigned short* Ag = A  + (size_t)(bm + srow) * K + skc;
  const unsigned short* Bg = Wc + (size_t)(bn + srow) * K + skc;

  unsigned short* Abase = lds;
  unsigned short* Bbase = lds + 24576;
  const int stoff = wid * 512;                    // wave-uniform dest (r=0)

  // fragment read offsets (ushort units); row stride 32, swizzled chunk
  const int fr  = lane & 15;
  const int sig = ((lane >> 4) ^ ((lane >> 1) & 3)) * 8;
  const int aro = (wr * 128 + fr) * 32 + sig;     // + (m>=4)*2048 + i*512
  const int bro = (wc * 64 + fr) * 32 + sig;      // + j*512

  auto stA = [&](int kt, int b, int r) {
    __builtin_amdgcn_global_load_lds(
      (const __attribute__((address_space(1))) void*)(Ag + (size_t)r * 128 * K + kt * 32),
      (__attribute__((address_space(3))) void*)(Abase + b * 8192 + r * 4096 + stoff),
      16, 0, 0);
  };
  auto stB = [&](int kt, int b, int r) {
    __builtin_amdgcn_global_load_lds(
      (const __attribute__((address_space(1))) void*)(Bg + (size_t)r * 128 * K + kt * 32),
      (__attribute__((address_space(3))) void*)(Bbase + b * 8192 + r * 4096 + stoff),
      16, 0, 0);
  };

  f32x4 acc[8][4];
#pragma unroll
  for (int i = 0; i < 8; ++i)
#pragma unroll
    for (int j = 0; j < 4; ++j) acc[i][j] = (f32x4){0.f, 0.f, 0.f, 0.f};

  // prologue: tile0 -> buf0, tile1 -> buf1; wait tile0 (4 newest remain)
  stA(0, 0, 0); stA(0, 0, 1); stB(0, 0, 0); stB(0, 0, 1);
  stA(1, 1, 0); stA(1, 1, 1); stB(1, 1, 0); stB(1, 1, 1);
  asm volatile("s_waitcnt vmcnt(4)" ::: "memory");
  __builtin_amdgcn_s_barrier();
  __builtin_amdgcn_sched_barrier(0);

  int c = 0;
#pragma unroll 1
  for (int kt = 0; kt < NT; ++kt) {
    const unsigned short* Ab = Abase + c * 8192;
    const unsigned short* Bb = Bbase + c * 8192;
    int nb = c + 2; if (nb >= 3) nb -= 3;
    const bool st = (kt < NT - 2);

    // ---- phase A: stage A(kt+2) | ds_read m0..3 + B | bar | 16 MFMA | bar
    if (st) { stA(kt + 2, nb, 0); stA(kt + 2, nb, 1); }
    short8 af0[4], bfr[4];
#pragma unroll
    for (int i = 0; i < 4; ++i) af0[i] = *(const short8*)(Ab + aro + i * 512);
#pragma unroll
    for (int j = 0; j < 4; ++j) bfr[j] = *(const short8*)(Bb + bro + j * 512);
    __builtin_amdgcn_s_barrier();
    asm volatile("s_waitcnt lgkmcnt(0)" ::: "memory");
    __builtin_amdgcn_sched_barrier(0);
    __builtin_amdgcn_s_setprio(1);
#pragma unroll
    for (int i = 0; i < 4; ++i)
#pragma unroll
      for (int j = 0; j < 4; ++j)
        acc[i][j] = __builtin_amdgcn_mfma_f32_16x16x32_bf16(af0[i], bfr[j], acc[i][j], 0, 0, 0);
    __builtin_amdgcn_s_setprio(0);
    __builtin_amdgcn_s_barrier();

    // ---- phase B: stage B(kt+2) | ds_read m4..7 | bar | 16 MFMA | vm | bar
    if (st) { stB(kt + 2, nb, 0); stB(kt + 2, nb, 1); }
    short8 af1[4];
#pragma unroll
    for (int i = 0; i < 4; ++i) af1[i] = *(const short8*)(Ab + aro + 2048 + i * 512);
    __builtin_amdgcn_s_barrier();
    asm volatile("s_waitcnt lgkmcnt(0)" ::: "memory");
    __builtin_amdgcn_sched_barrier(0);
    __builtin_amdgcn_s_setprio(1);
#pragma unroll
    for (int i = 0; i < 4; ++i)
#pragma unroll
      for (int j = 0; j < 4; ++j)
        acc[4 + i][j] = __builtin_amdgcn_mfma_f32_16x16x32_bf16(af1[i], bfr[j], acc[4 + i][j], 0, 0, 0);
    __builtin_amdgcn_s_setprio(0);
    if (st)                 asm volatile("s_waitcnt vmcnt(4)" ::: "memory");
    else if (kt == NT - 2)  asm volatile("s_waitcnt vmcnt(0)" ::: "memory");
    __builtin_amdgcn_s_barrier();
    c = (c == 2) ? 0 : c + 1;
  }

  // ---- epilogue: route by segment (q f32, k/v bf16 interleaved), add bias
  const int seg = bn >> 11;                        // 0:q 1:k 2:v
  const float* bp = (seg == 0) ? bq : (seg == 1) ? bk : bv;
  float bias_j[4];
#pragma unroll
  for (int j = 0; j < 4; ++j)
    bias_j[j] = bp[(bn + wc * 64 + j * 16 + fr) & 2047];
  const int er = (lane >> 4) * 4;
  const int kvoff = (seg == 2) ? 2048 : 0;
#pragma unroll
  for (int I = 0; I < 8; ++I) {
    int row = bm + wr * 128 + I * 16 + er;
#pragma unroll
    for (int j = 0; j < 4; ++j) {
      int col = (bn + wc * 64 + j * 16 + fr) & 2047;
#pragma unroll
      for (int r = 0; r < 4; ++r) {
        float val = acc[I][j][r] + bias_j[j];
        if (seg == 0)
          qout[(size_t)(row + r) * 2048 + col] = val;
        else
          kvb[(size_t)(row + r) * 4096 + kvoff + col] = f2bf(val);
      }
    }
  }
}

// ------------------------------------------------------------- FFT core ---
// 2048-pt FFT, 256 threads, radix 8-8-8-4 macro-stages, register butterflies.
__device__ __forceinline__ int XS(int i){ return i ^ (((i >> 5) ^ (i >> 10)) & 31); }
__device__ __forceinline__ int TS(int i){ return i ^ ((i >> 5) & 31); }

__device__ __forceinline__ float2 mulmi(float2 w){ return mkf2(w.y, -w.x); }   // w * (-i)
__device__ __forceinline__ float2 mulw8(float2 w){                              // w * e^{-i pi/4}
  const float c = 0.70710678118654752f;
  return mkf2(c * (w.x + w.y), c * (w.y - w.x));
}
__device__ __forceinline__ void bfly(float2& a, float2& b, float2 w){
  float2 v = cmulf(w, b);
  b = mkf2(a.x - v.x, a.y - v.y);
  a = mkf2(a.x + v.x, a.y + v.y);
}
__device__ __forceinline__ void bflyc(float2& a, float2& b, float2 w){
  float2 d = mkf2(a.x - b.x, a.y - b.y);
  a = mkf2(a.x + b.x, a.y + b.y);
  b = mkf2(fmaf(d.x, w.x, d.y * w.y), fmaf(d.y, w.x, -d.x * w.y));  // d * conj(w)
}

__device__ __forceinline__ void fwd8(float2 e[8], float2 wA, float2 wB0, float2 wC0){
  bfly(e[0], e[1], wA); bfly(e[2], e[3], wA); bfly(e[4], e[5], wA); bfly(e[6], e[7], wA);
  float2 wB1 = mulmi(wB0);
  bfly(e[0], e[2], wB0); bfly(e[1], e[3], wB1); bfly(e[4], e[6], wB0); bfly(e[5], e[7], wB1);
  float2 wC1 = mulw8(wC0), wC2 = mulmi(wC0), wC3 = mulmi(wC1);
  bfly(e[0], e[4], wC0); bfly(e[1], e[5], wC1); bfly(e[2], e[6], wC2); bfly(e[3], e[7], wC3);
}
__device__ __forceinline__ void inv8(float2 e[8], float2 wA, float2 wB0, float2 wC0){
  float2 wC1 = mulw8(wC0), wC2 = mulmi(wC0), wC3 = mulmi(wC1);
  bflyc(e[0], e[4], wC0); bflyc(e[1], e[5], wC1); bflyc(e[2], e[6], wC2); bflyc(e[3], e[7], wC3);
  float2 wB1 = mulmi(wB0);
  bflyc(e[0], e[2], wB0); bflyc(e[1], e[3], wB1); bflyc(e[4], e[6], wB0); bflyc(e[5], e[7], wB1);
  bflyc(e[0], e[1], wA); bflyc(e[2], e[3], wA); bflyc(e[4], e[5], wA); bflyc(e[6], e[7], wA);
}

__device__ __forceinline__ float2 twld(const float* twr, const float* twi, int i){
  int s = TS(i);
  return mkf2(twr[s], twi[s]);
}

__device__ void fft_fwd(float2* X, const float* twr, const float* twi, int t)
{
  const float2 one = mkf2(1.f, 0.f);
  {                                   // MS1
    int b = 8 * t;
    float2 e[8];
#pragma unroll
    for (int r = 0; r < 8; ++r) e[r] = X[XS(b + r)];
    fwd8(e, one, one, one);
#pragma unroll
    for (int r = 0; r < 8; ++r) X[XS(b + r)] = e[r];
  }
  __syncthreads();
  {                                   // MS2
    int u = t >> 5, b = 64 * (t & 31) + u;
    float2 e[8];
#pragma unroll
    for (int r = 0; r < 8; ++r) e[r] = X[XS(b + 8 * r)];
    fwd8(e, twld(twr,twi,128*u), twld(twr,twi,64*u), twld(twr,twi,32*u));
#pragma unroll
    for (int r = 0; r < 8; ++r) X[XS(b + 8 * r)] = e[r];
  }
  __syncthreads();
  {                                   // MS3
    int u = t & 63, b = 512 * (t >> 6) + u;
    float2 e[8];
#pragma unroll
    for (int r = 0; r < 8; ++r) e[r] = X[XS(b + 64 * r)];
    fwd8(e, twld(twr,twi,16*u), twld(twr,twi,8*u), twld(twr,twi,4*u));
#pragma unroll
    for (int r = 0; r < 8; ++r) X[XS(b + 64 * r)] = e[r];
  }
  __syncthreads();
#pragma unroll
  for (int h = 0; h < 2; ++h) {       // MS4: radix-4
    int u = t + 256 * h;
    float2 f[4];
#pragma unroll
    for (int r = 0; r < 4; ++r) f[r] = X[XS(u + 512 * r)];
    float2 wA = twld(twr,twi,2*u), wB0 = twld(twr,twi,u), wB1 = mulmi(wB0);
    bfly(f[0], f[1], wA);  bfly(f[2], f[3], wA);
    bfly(f[0], f[2], wB0); bfly(f[1], f[3], wB1);
#pragma unroll
    for (int r = 0; r < 4; ++r) X[XS(u + 512 * r)] = f[r];
  }
  __syncthreads();
}

__device__ void fft_inv(float2* X, const float* twr, const float* twi, int t)
{
  const float2 one = mkf2(1.f, 0.f);
#pragma unroll
  for (int h = 0; h < 2; ++h) {       // MS4'
    int u = t + 256 * h;
    float2 f[4];
#pragma unroll
    for (int r = 0; r < 4; ++r) f[r] = X[XS(u + 512 * r)];
    float2 wA = twld(twr,twi,2*u), wB0 = twld(twr,twi,u), wB1 = mulmi(wB0);
    bflyc(f[0], f[2], wB0); bflyc(f[1], f[3], wB1);
    bflyc(f[0], f[1], wA);  bflyc(f[2], f[3], wA);
#pragma unroll
    for (int r = 0; r < 4; ++r) X[XS(u + 512 * r)] = f[r];
  }
  __syncthreads();
  {                                   // MS3'
    int u = t & 63, b = 512 * (t >> 6) + u;
    float2 e[8];
#pragma unroll
    for (int r = 0; r < 8; ++r) e[r] = X[XS(b + 64 * r)];
    inv8(e, twld(twr,twi,16*u), twld(twr,twi,8*u), twld(twr,twi,4*u));
#pragma unroll
    for (int r = 0; r < 8; ++r) X[XS(b + 64 * r)] = e[r];
  }
  __syncthreads();
  {                                   // MS2'
    int u = t >> 5, b = 64 * (t & 31) + u;
    float2 e[8];
#pragma unroll
    for (int r = 0; r < 8; ++r) e[r] = X[XS(b + 8 * r)];
    inv8(e, twld(twr,twi,128*u), twld(twr,twi,64*u), twld(twr,twi,32*u));
#pragma unroll
    for (int r = 0; r < 8; ++r) X[XS(b + 8 * r)] = e[r];
  }
  __syncthreads();
  {                                   // MS1'
    int b = 8 * t;
    float2 e[8];
#pragma unroll
    for (int r = 0; r < 8; ++r) e[r] = X[XS(b + r)];
    inv8(e, one, one, one);
#pragma unroll
    for (int r = 0; r < 8; ++r) X[XS(b + r)] = e[r];
  }
  __syncthreads();
}

// ------------------------------------------------------- twiddle table ----
__global__ __launch_bounds__(256)
void twiddle_init(float2* __restrict__ twg)
{
  int i = blockIdx.x * 256 + threadIdx.x;
  if (i < HALF_D) {
    float sv, cv;
    sincosf(-6.283185307179586f * (float)i / (float)D_DIM, &sv, &cv);
    twg[i] = mkf2(cv, sv);
  }
}

// ---------------------------------------------------------- FFT(k,v)·mul --
// kvb row r: [k bf16 x2048 | v bf16 x2048] (8 KB). One complex FFT of
// (k + i·v) recovers both spectra; writes packed half-spectrum of
// unit(Fk)·unit(Fv) IN PLACE over the same 8 KB row slot.
__global__ __launch_bounds__(256)
void fftkv_kernel(unsigned short* __restrict__ kvb, const float2* __restrict__ twg)
{
  __shared__ float2 X[D_DIM];
  __shared__ float twr[HALF_D], twi[HALF_D];
  const int t = threadIdx.x;
  const size_t row = blockIdx.x;
  const unsigned short* kvrow = kvb + row * 4096;

  for (int i = t; i < HALF_D; i += 256) {
    float2 w = twg[i]; int s = TS(i); twr[s] = w.x; twi[s] = w.y;
  }
  for (int i = t; i < D_DIM; i += 256) {
    int p = __brev((unsigned)i) >> 21;
    X[XS(p)] = mkf2(bf2f(kvrow[i]), bf2f(kvrow[2048 + i]));
  }
  __syncthreads();
  fft_fwd(X, twr, twi, t);

  float2* outp = (float2*)(kvb + row * 4096);
  for (int d = t; d < HALF_D; d += 256) {
    float2 p;
    if (d == 0) {
      float2 z0 = X[XS(0)], zn = X[XS(HALF_D)];
      float k0 = z0.x, v0 = z0.y, kn = zn.x, vn = zn.y;
      float p0 = (k0 / (fabsf(k0) + EPS_)) * (v0 / (fabsf(v0) + EPS_));
      float pn = (kn / (fabsf(kn) + EPS_)) * (vn / (fabsf(vn) + EPS_));
      p = mkf2(p0, pn);
    } else {
      float2 A = X[XS(d)];
      float2 Bc = X[XS(D_DIM - d)];
      float2 Bj = mkf2(Bc.x, -Bc.y);
      float2 Fk = mkf2(0.5f * (A.x + Bj.x), 0.5f * (A.y + Bj.y));
      float2 tt = mkf2(0.5f * (A.x - Bj.x), 0.5f * (A.y - Bj.y));
      float2 Fv = mkf2(tt.y, -tt.x);
      float sa = 1.f / (sqrtf(Fk.x*Fk.x + Fk.y*Fk.y) + EPS_);
      float sb = 1.f / (sqrtf(Fv.x*Fv.x + Fv.y*Fv.y) + EPS_);
      p = cmulf(Fk, Fv);
      float sc = sa * sb;
      p.x *= sc; p.y *= sc;
    }
    outp[d] = p;
  }
}

// --------------------------------------------------------------- scan -----
__global__ __launch_bounds__(256)
void scan_partial(const float2* __restrict__ kv, float2* __restrict__ part)
{
  int gid = blockIdx.x * 256 + threadIdx.x;
  int d = gid & (HALF_D - 1);
  int chunk = (gid >> 10) & (NCHUNK - 1);
  int b = gid >> 16;
  const float2* p = kv + ((size_t)(b * S_DIM + chunk * CHLEN) * HALF_D) + d;
  float2 acc = mkf2(0.f, 0.f);
  for (int s = 0; s < CHLEN; ++s) {
    float2 v = p[(size_t)s * HALF_D];
    acc.x += v.x; acc.y += v.y;
  }
  part[gid] = acc;
}

__global__ __launch_bounds__(256)
void scan_offsets(float2* __restrict__ part)
{
  int gid = blockIdx.x * 256 + threadIdx.x;
  int d = gid & (HALF_D - 1);
  int b = gid >> 10;
  float2* p = part + (size_t)b * (NCHUNK * HALF_D) + d;
  float2 acc = mkf2(0.f, 0.f);
  for (int c = 0; c < NCHUNK; ++c) {
    float2 v = p[(size_t)c * HALF_D];
    p[(size_t)c * HALF_D] = acc;
    acc.x += v.x; acc.y += v.y;
  }
}

__global__ __launch_bounds__(256)
void scan_apply(float2* __restrict__ kv, const float2* __restrict__ part)
{
  int gid = blockIdx.x * 256 + threadIdx.x;
  int d = gid & (HALF_D - 1);
  int chunk = (gid >> 10) & (NCHUNK - 1);
  int b = gid >> 16;
  float2* p = kv + ((size_t)(b * S_DIM + chunk * CHLEN) * HALF_D) + d;
  float2 acc = part[gid];
  for (int s = 0; s < CHLEN; ++s) {
    float2 v = p[(size_t)s * HALF_D];
    acc.x += v.x; acc.y += v.y;
    p[(size_t)s * HALF_D] = acc;
  }
}

// --------------------------------------------------------------- final ----
__global__ __launch_bounds__(256)
void final_kernel(float* __restrict__ qo, const float2* __restrict__ mem,
                  const float* __restrict__ base, const float* __restrict__ gate,
                  const float2* __restrict__ twg)
{
  __shared__ float2 X[D_DIM];
  __shared__ float twr[HALF_D], twi[HALF_D];
  const int t = threadIdx.x;
  const size_t row = blockIdx.x;
  float* qrow = qo + row * D_DIM;
  const float2* mrow = mem + row * HALF_D;

  for (int i = t; i < HALF_D; i += 256) {
    float2 w = twg[i]; int s = TS(i); twr[s] = w.x; twi[s] = w.y;
  }
  for (int i = t; i < D_DIM; i += 256) {
    int p = __brev((unsigned)i) >> 21;
    X[XS(p)] = mkf2(qrow[i], 0.f);
  }
  __syncthreads();
  fft_fwd(X, twr, twi, t);

  for (int d = t; d < HALF_D; d += 256) {
    if (d == 0) {
      float2 fm = mrow[0];
      float2 f0 = X[XS(0)], f1 = X[XS(HALF_D)];
      X[XS(0)]      = mkf2(f0.x * fm.x, -f0.y * fm.x);
      X[XS(HALF_D)] = mkf2(f1.x * fm.y, -f1.y * fm.y);
    } else {
      float2 fm = mrow[d];
      float2 fq = X[XS(d)];
      X[XS(d)] = mkf2(fq.x*fm.x + fq.y*fm.y, fq.x*fm.y - fq.y*fm.x);
      float2 f2 = X[XS(D_DIM - d)];
      X[XS(D_DIM - d)] = mkf2(f2.x*fm.x - f2.y*fm.y, -f2.x*fm.y - f2.y*fm.x);
    }
  }
  __syncthreads();
  fft_inv(X, twr, twi, t);

  const float gv = gate[0] * (1.f / (float)D_DIM);
  const float* brow = base + row * D_DIM;
  for (int i = t; i < D_DIM; i += 256) {
    int p = __brev((unsigned)i) >> 21;
    qrow[i] = brow[i] + gv * X[XS(p)].x;
  }
}

// ------------------------------------------------------------ launcher ----
extern "C" void kernel_launch(void* const* d_in, const int* in_sizes, int n_in,
                              void* d_out, int out_size, void* d_ws, size_t ws_size,
                              hipStream_t stream)
{
  const float* hs   = (const float*)d_in[0];
  const float* base = (const float*)d_in[1];
  const float* Wq   = (const float*)d_in[2];
  const float* bq   = (const float*)d_in[3];
  const float* Wk   = (const float*)d_in[4];
  const float* bk   = (const float*)d_in[5];
  const float* Wv   = (const float*)d_in[6];
  const float* bv   = (const float*)d_in[7];
  const float* gate = (const float*)d_in[8];
  float* out  = (float*)d_out;

  // workspace layout (126.8 MB):
  //   hsb  bf16 [8192][2048]   (first 8KB reused as twiddle table post-GEMM)
  //   wqb|wkb|wvb bf16 [6144][2048] contiguous (fused weight)
  //   kvb  [8192] x 8KB rows: [k bf16 x2048 | v bf16 x2048] -> packed Fkv/Fmem
  //   part f32x2 [2][64][1024]
  char* ws = (char*)d_ws;
  unsigned short* hsb = (unsigned short*)ws;
  unsigned short* wqb = (unsigned short*)(ws + 33554432);
  unsigned short* wkb = wqb + (size_t)D_DIM * D_DIM;
  unsigned short* wvb = wkb + (size_t)D_DIM * D_DIM;
  unsigned short* kvb = (unsigned short*)(ws + 58720256);
  float2* part = (float2*)(ws + 58720256 + 67108864);
  float2* twg  = (float2*)ws;   // overwrites hsb AFTER the GEMM consumed it

  {
    int n8 = (NROW * D_DIM) / 8;
    cvt_f32_bf16<<<n8 / 256, 256, 0, stream>>>(hs, hsb, n8);
    int w8 = (D_DIM * D_DIM) / 8;
    cvt_f32_bf16<<<w8 / 256, 256, 0, stream>>>(Wq, wqb, w8);
    cvt_f32_bf16<<<w8 / 256, 256, 0, stream>>>(Wk, wkb, w8);
    cvt_f32_bf16<<<w8 / 256, 256, 0, stream>>>(Wv, wvb, w8);
  }

  gemm_fused<<<768, 512, 0, stream>>>(hsb, wqb, bq, bk, bv, out, kvb);

  twiddle_init<<<4, 256, 0, stream>>>(twg);

  fftkv_kernel<<<NROW, 256, 0, stream>>>(kvb, twg);

  scan_partial<<<(B_DIM * NCHUNK * HALF_D) / 256, 256, 0, stream>>>(
      (const float2*)kvb, part);
  scan_offsets<<<(B_DIM * HALF_D) / 256, 256, 0, stream>>>(part);
  scan_apply<<<(B_DIM * NCHUNK * HALF_D) / 256, 256, 0, stream>>>(
      (float2*)kvb, part);

  final_kernel<<<NROW, 256, 0, stream>>>(out, (const float2*)kvb, base, gate, twg);
}

// Round 6
// 404.389 us; speedup vs baseline: 7.4778x; 1.0716x over previous
//
#include <hip/hip_runtime.h>
#include <math.h>

constexpr int D_DIM  = 2048;   // feature dim (FFT length)
constexpr int HALF_D = 1024;
constexpr int B_DIM  = 2;
constexpr int S_DIM  = 4096;
constexpr int NROW   = B_DIM * S_DIM;      // 8192
constexpr int NCHUNK = 64;                 // scan chunks along S
constexpr int CHLEN  = S_DIM / NCHUNK;     // 64
constexpr float EPS_ = 1e-8f;

typedef __attribute__((ext_vector_type(8))) short  short8;   // bf16x8 frag
typedef __attribute__((ext_vector_type(8))) unsigned short ushort8;
typedef __attribute__((ext_vector_type(4))) float  f32x4;    // MFMA acc

__device__ __forceinline__ float2 mkf2(float x, float y){ float2 r; r.x=x; r.y=y; return r; }
__device__ __forceinline__ float2 cmulf(float2 a, float2 b){
  return mkf2(fmaf(a.x, b.x, -a.y*b.y), fmaf(a.x, b.y, a.y*b.x));
}
__device__ __forceinline__ unsigned short f2bf(float x){
  unsigned u = __float_as_uint(x);
  u += 0x7fff + ((u >> 16) & 1);           // round-to-nearest-even
  return (unsigned short)(u >> 16);
}
__device__ __forceinline__ float bf2f(unsigned short h){
  return __uint_as_float(((unsigned)h) << 16);
}

// ------------------------------------------------------------ fp32→bf16 ---
__global__ __launch_bounds__(256)
void cvt_f32_bf16(const float* __restrict__ in, unsigned short* __restrict__ out, int n8)
{
  int i = blockIdx.x * 256 + threadIdx.x;
  if (i >= n8) return;
  const float4* p = (const float4*)in + (size_t)i * 2;
  float4 a = p[0], b = p[1];
  ushort8 o;
  o[0]=f2bf(a.x); o[1]=f2bf(a.y); o[2]=f2bf(a.z); o[3]=f2bf(a.w);
  o[4]=f2bf(b.x); o[5]=f2bf(b.y); o[6]=f2bf(b.z); o[7]=f2bf(b.w);
  *(ushort8*)(out + (size_t)i * 8) = o;
}

// ---------------- fused q/k/v 256x128 MFMA GEMM (tri-buffer, 2 blocks/CU) -
// A [8192][2048] bf16, Wc [6144][2048] bf16 (Wq|Wk|Wv rows concatenated).
// C = A @ Wc^T + bias; q -> bf16 qb, k/v -> bf16 interleaved kvb rows.
// 4 waves (2Mx2N), per-wave 128x64 output, BK=32, tri-buffer 72KB LDS ->
// 2 blocks/CU (cross-block stall overlap), staging 2 K-tiles ahead, counted
// s_waitcnt vmcnt(6), XOR-swizzled LDS (conflict-free), setprio on MFMA.
__global__ __launch_bounds__(256, 2)
void gemm_fused(const unsigned short* __restrict__ A,
                const unsigned short* __restrict__ Wc,
                const float* __restrict__ bq, const float* __restrict__ bk,
                const float* __restrict__ bv,
                unsigned short* __restrict__ qb, unsigned short* __restrict__ kvb)
{
  constexpr int K = 2048, NT = K / 32;            // 64 K-tiles
  __shared__ unsigned short lds[36864];           // 72 KB: A 3x16KB + B 3x8KB
  const int tid  = threadIdx.x;
  const int wid  = tid >> 6, lane = tid & 63;
  const int wr   = wid >> 1, wc = wid & 1;

  // XCD-bijective swizzle: 1536 blocks, 192/XCD; chunk = 4 M-panels x 48 N
  int bid = blockIdx.x;
  int sw  = (bid & 7) * 192 + (bid >> 3);
  const int bm = (sw / 48) * 256, bn = (sw % 48) * 128;

  // staging: instr r covers rows r*64 + tid/4; stored chunk tid&3 holds
  // k-chunk (tid&3) ^ ((row>>1)&3) = (tid&3) ^ ((tid>>3)&3)
  const int srow = tid >> 2;
  const int skc  = ((tid & 3) ^ ((tid >> 3) & 3)) * 8;
  const unsigned short* Ag = A  + (size_t)(bm + srow) * K + skc;
  const unsigned short* Bg = Wc + (size_t)(bn + srow) * K + skc;

  unsigned short* Abase = lds;
  unsigned short* Bbase = lds + 24576;
  const int stoff = wid * 512;                    // wave-uniform dest

  // fragment read offsets (ushort units); row stride 32, swizzled chunk
  const int fr  = lane & 15;
  const int sig = ((lane >> 4) ^ ((lane >> 1) & 3)) * 8;
  const int aro = (wr * 128 + fr) * 32 + sig;     // + (m>=4)*2048 + i*512
  const int bro = (wc * 64 + fr) * 32 + sig;      // + j*512

  auto stA = [&](int kt, int b, int r) {
    __builtin_amdgcn_global_load_lds(
      (const __attribute__((address_space(1))) void*)(Ag + (size_t)r * 64 * K + kt * 32),
      (__attribute__((address_space(3))) void*)(Abase + b * 8192 + r * 2048 + stoff),
      16, 0, 0);
  };
  auto stB = [&](int kt, int b, int r) {
    __builtin_amdgcn_global_load_lds(
      (const __attribute__((address_space(1))) void*)(Bg + (size_t)r * 64 * K + kt * 32),
      (__attribute__((address_space(3))) void*)(Bbase + b * 4096 + r * 2048 + stoff),
      16, 0, 0);
  };

  f32x4 acc[8][4];
#pragma unroll
  for (int i = 0; i < 8; ++i)
#pragma unroll
    for (int j = 0; j < 4; ++j) acc[i][j] = (f32x4){0.f, 0.f, 0.f, 0.f};

  // prologue: tile0 -> buf0, tile1 -> buf1; wait tile0 (6 newest remain)
  stA(0, 0, 0); stA(0, 0, 1); stA(0, 0, 2); stA(0, 0, 3); stB(0, 0, 0); stB(0, 0, 1);
  stA(1, 1, 0); stA(1, 1, 1); stA(1, 1, 2); stA(1, 1, 3); stB(1, 1, 0); stB(1, 1, 1);
  asm volatile("s_waitcnt vmcnt(6)" ::: "memory");
  __builtin_amdgcn_s_barrier();
  __builtin_amdgcn_sched_barrier(0);

  int c = 0;
#pragma unroll 1
  for (int kt = 0; kt < NT; ++kt) {
    const unsigned short* Ab = Abase + c * 8192;
    const unsigned short* Bb = Bbase + c * 4096;
    int nb = c + 2; if (nb >= 3) nb -= 3;
    const bool st = (kt < NT - 2);

    // ---- phase A: stage A(kt+2) | ds_read m0..3 + B | bar | 16 MFMA | bar
    if (st) { stA(kt + 2, nb, 0); stA(kt + 2, nb, 1); stA(kt + 2, nb, 2); stA(kt + 2, nb, 3); }
    short8 af0[4], bfr[4];
#pragma unroll
    for (int i = 0; i < 4; ++i) af0[i] = *(const short8*)(Ab + aro + i * 512);
#pragma unroll
    for (int j = 0; j < 4; ++j) bfr[j] = *(const short8*)(Bb + bro + j * 512);
    __builtin_amdgcn_s_barrier();
    asm volatile("s_waitcnt lgkmcnt(0)" ::: "memory");
    __builtin_amdgcn_sched_barrier(0);
    __builtin_amdgcn_s_setprio(1);
#pragma unroll
    for (int i = 0; i < 4; ++i)
#pragma unroll
      for (int j = 0; j < 4; ++j)
        acc[i][j] = __builtin_amdgcn_mfma_f32_16x16x32_bf16(af0[i], bfr[j], acc[i][j], 0, 0, 0);
    __builtin_amdgcn_s_setprio(0);
    __builtin_amdgcn_s_barrier();

    // ---- phase B: stage B(kt+2) | ds_read m4..7 | bar | 16 MFMA | vm | bar
    if (st) { stB(kt + 2, nb, 0); stB(kt + 2, nb, 1); }
    short8 af1[4];
#pragma unroll
    for (int i = 0; i < 4; ++i) af1[i] = *(const short8*)(Ab + aro + 2048 + i * 512);
    __builtin_amdgcn_s_barrier();
    asm volatile("s_waitcnt lgkmcnt(0)" ::: "memory");
    __builtin_amdgcn_sched_barrier(0);
    __builtin_amdgcn_s_setprio(1);
#pragma unroll
    for (int i = 0; i < 4; ++i)
#pragma unroll
      for (int j = 0; j < 4; ++j)
        acc[4 + i][j] = __builtin_amdgcn_mfma_f32_16x16x32_bf16(af1[i], bfr[j], acc[4 + i][j], 0, 0, 0);
    __builtin_amdgcn_s_setprio(0);
    if (st)                 asm volatile("s_waitcnt vmcnt(6)" ::: "memory");
    else if (kt == NT - 2)  asm volatile("s_waitcnt vmcnt(0)" ::: "memory");
    __builtin_amdgcn_s_barrier();
    c = (c == 2) ? 0 : c + 1;
  }

  // ---- epilogue: route by segment; all outputs bf16
  const int seg = bn >> 11;                        // 0:q 1:k 2:v
  const float* bp = (seg == 0) ? bq : (seg == 1) ? bk : bv;
  float bias_j[4];
#pragma unroll
  for (int j = 0; j < 4; ++j)
    bias_j[j] = bp[(bn + wc * 64 + j * 16 + fr) & 2047];
  const int er = (lane >> 4) * 4;
  unsigned short* dst = (seg == 0) ? qb : kvb;
  const size_t rstride = (seg == 0) ? 2048 : 4096;
  const int coff = (seg == 2) ? 2048 : 0;
#pragma unroll
  for (int I = 0; I < 8; ++I) {
    int row = bm + wr * 128 + I * 16 + er;
#pragma unroll
    for (int j = 0; j < 4; ++j) {
      int col = (bn + wc * 64 + j * 16 + fr) & 2047;
#pragma unroll
      for (int r = 0; r < 4; ++r) {
        float val = acc[I][j][r] + bias_j[j];
        dst[(size_t)(row + r) * rstride + coff + col] = f2bf(val);
      }
    }
  }
}

// ------------------------------------------------------------- FFT core ---
// 2048-pt FFT, 256 threads, radix 8-8-8-4 macro-stages, register butterflies.
__device__ __forceinline__ int XS(int i){ return i ^ (((i >> 5) ^ (i >> 10)) & 31); }
__device__ __forceinline__ int TS(int i){ return i ^ ((i >> 5) & 31); }

__device__ __forceinline__ float2 mulmi(float2 w){ return mkf2(w.y, -w.x); }   // w * (-i)
__device__ __forceinline__ float2 mulw8(float2 w){                              // w * e^{-i pi/4}
  const float c = 0.70710678118654752f;
  return mkf2(c * (w.x + w.y), c * (w.y - w.x));
}
__device__ __forceinline__ void bfly(float2& a, float2& b, float2 w){
  float2 v = cmulf(w, b);
  b = mkf2(a.x - v.x, a.y - v.y);
  a = mkf2(a.x + v.x, a.y + v.y);
}
__device__ __forceinline__ void bflyc(float2& a, float2& b, float2 w){
  float2 d = mkf2(a.x - b.x, a.y - b.y);
  a = mkf2(a.x + b.x, a.y + b.y);
  b = mkf2(fmaf(d.x, w.x, d.y * w.y), fmaf(d.y, w.x, -d.x * w.y));  // d * conj(w)
}

__device__ __forceinline__ void fwd8(float2 e[8], float2 wA, float2 wB0, float2 wC0){
  bfly(e[0], e[1], wA); bfly(e[2], e[3], wA); bfly(e[4], e[5], wA); bfly(e[6], e[7], wA);
  float2 wB1 = mulmi(wB0);
  bfly(e[0], e[2], wB0); bfly(e[1], e[3], wB1); bfly(e[4], e[6], wB0); bfly(e[5], e[7], wB1);
  float2 wC1 = mulw8(wC0), wC2 = mulmi(wC0), wC3 = mulmi(wC1);
  bfly(e[0], e[4], wC0); bfly(e[1], e[5], wC1); bfly(e[2], e[6], wC2); bfly(e[3], e[7], wC3);
}
__device__ __forceinline__ void inv8(float2 e[8], float2 wA, float2 wB0, float2 wC0){
  float2 wC1 = mulw8(wC0), wC2 = mulmi(wC0), wC3 = mulmi(wC1);
  bflyc(e[0], e[4], wC0); bflyc(e[1], e[5], wC1); bflyc(e[2], e[6], wC2); bflyc(e[3], e[7], wC3);
  float2 wB1 = mulmi(wB0);
  bflyc(e[0], e[2], wB0); bflyc(e[1], e[3], wB1); bflyc(e[4], e[6], wB0); bflyc(e[5], e[7], wB1);
  bflyc(e[0], e[1], wA); bflyc(e[2], e[3], wA); bflyc(e[4], e[5], wA); bflyc(e[6], e[7], wA);
}

__device__ __forceinline__ float2 twld(const float* twr, const float* twi, int i){
  int s = TS(i);
  return mkf2(twr[s], twi[s]);
}

__device__ void fft_fwd(float2* X, const float* twr, const float* twi, int t)
{
  const float2 one = mkf2(1.f, 0.f);
  {                                   // MS1
    int b = 8 * t;
    float2 e[8];
#pragma unroll
    for (int r = 0; r < 8; ++r) e[r] = X[XS(b + r)];
    fwd8(e, one, one, one);
#pragma unroll
    for (int r = 0; r < 8; ++r) X[XS(b + r)] = e[r];
  }
  __syncthreads();
  {                                   // MS2
    int u = t >> 5, b = 64 * (t & 31) + u;
    float2 e[8];
#pragma unroll
    for (int r = 0; r < 8; ++r) e[r] = X[XS(b + 8 * r)];
    fwd8(e, twld(twr,twi,128*u), twld(twr,twi,64*u), twld(twr,twi,32*u));
#pragma unroll
    for (int r = 0; r < 8; ++r) X[XS(b + 8 * r)] = e[r];
  }
  __syncthreads();
  {                                   // MS3
    int u = t & 63, b = 512 * (t >> 6) + u;
    float2 e[8];
#pragma unroll
    for (int r = 0; r < 8; ++r) e[r] = X[XS(b + 64 * r)];
    fwd8(e, twld(twr,twi,16*u), twld(twr,twi,8*u), twld(twr,twi,4*u));
#pragma unroll
    for (int r = 0; r < 8; ++r) X[XS(b + 64 * r)] = e[r];
  }
  __syncthreads();
#pragma unroll
  for (int h = 0; h < 2; ++h) {       // MS4: radix-4
    int u = t + 256 * h;
    float2 f[4];
#pragma unroll
    for (int r = 0; r < 4; ++r) f[r] = X[XS(u + 512 * r)];
    float2 wA = twld(twr,twi,2*u), wB0 = twld(twr,twi,u), wB1 = mulmi(wB0);
    bfly(f[0], f[1], wA);  bfly(f[2], f[3], wA);
    bfly(f[0], f[2], wB0); bfly(f[1], f[3], wB1);
#pragma unroll
    for (int r = 0; r < 4; ++r) X[XS(u + 512 * r)] = f[r];
  }
  __syncthreads();
}

__device__ void fft_inv(float2* X, const float* twr, const float* twi, int t)
{
  const float2 one = mkf2(1.f, 0.f);
#pragma unroll
  for (int h = 0; h < 2; ++h) {       // MS4'
    int u = t + 256 * h;
    float2 f[4];
#pragma unroll
    for (int r = 0; r < 4; ++r) f[r] = X[XS(u + 512 * r)];
    float2 wA = twld(twr,twi,2*u), wB0 = twld(twr,twi,u), wB1 = mulmi(wB0);
    bflyc(f[0], f[2], wB0); bflyc(f[1], f[3], wB1);
    bflyc(f[0], f[1], wA);  bflyc(f[2], f[3], wA);
#pragma unroll
    for (int r = 0; r < 4; ++r) X[XS(u + 512 * r)] = f[r];
  }
  __syncthreads();
  {                                   // MS3'
    int u = t & 63, b = 512 * (t >> 6) + u;
    float2 e[8];
#pragma unroll
    for (int r = 0; r < 8; ++r) e[r] = X[XS(b + 64 * r)];
    inv8(e, twld(twr,twi,16*u), twld(twr,twi,8*u), twld(twr,twi,4*u));
#pragma unroll
    for (int r = 0; r < 8; ++r) X[XS(b + 64 * r)] = e[r];
  }
  __syncthreads();
  {                                   // MS2'
    int u = t >> 5, b = 64 * (t & 31) + u;
    float2 e[8];
#pragma unroll
    for (int r = 0; r < 8; ++r) e[r] = X[XS(b + 8 * r)];
    inv8(e, twld(twr,twi,128*u), twld(twr,twi,64*u), twld(twr,twi,32*u));
#pragma unroll
    for (int r = 0; r < 8; ++r) X[XS(b + 8 * r)] = e[r];
  }
  __syncthreads();
  {                                   // MS1'
    int b = 8 * t;
    float2 e[8];
#pragma unroll
    for (int r = 0; r < 8; ++r) e[r] = X[XS(b + r)];
    inv8(e, one, one, one);
#pragma unroll
    for (int r = 0; r < 8; ++r) X[XS(b + r)] = e[r];
  }
  __syncthreads();
}

// ------------------------------------------------------- twiddle table ----
__global__ __launch_bounds__(256)
void twiddle_init(float2* __restrict__ twg)
{
  int i = blockIdx.x * 256 + threadIdx.x;
  if (i < HALF_D) {
    float sv, cv;
    sincosf(-6.283185307179586f * (float)i / (float)D_DIM, &sv, &cv);
    twg[i] = mkf2(cv, sv);
  }
}

// ---------------------------------------------------------- FFT(k,v)·mul --
// kvb row r: [k bf16 x2048 | v bf16 x2048]. One complex FFT of (k + i·v)
// recovers both spectra; writes packed half-spectrum of unit(Fk)·unit(Fv)
// as bf16 pairs (re,im) into the first 2048 ushorts of the row slot.
__global__ __launch_bounds__(256)
void fftkv_kernel(unsigned short* __restrict__ kvb, const float2* __restrict__ twg)
{
  __shared__ float2 X[D_DIM];
  __shared__ float twr[HALF_D], twi[HALF_D];
  const int t = threadIdx.x;
  const size_t row = blockIdx.x;
  const unsigned short* kvrow = kvb + row * 4096;

  for (int i = t; i < HALF_D; i += 256) {
    float2 w = twg[i]; int s = TS(i); twr[s] = w.x; twi[s] = w.y;
  }
  {
    int i0 = t * 8;
    ushort8 k8 = *(const ushort8*)(kvrow + i0);
    ushort8 v8 = *(const ushort8*)(kvrow + 2048 + i0);
#pragma unroll
    for (int r = 0; r < 8; ++r) {
      int i = i0 + r;
      int p = __brev((unsigned)i) >> 21;
      X[XS(p)] = mkf2(bf2f(k8[r]), bf2f(v8[r]));
    }
  }
  __syncthreads();
  fft_fwd(X, twr, twi, t);

  unsigned int* outp = (unsigned int*)(kvb + row * 4096);
  for (int d = t; d < HALF_D; d += 256) {
    float2 p;
    if (d == 0) {
      float2 z0 = X[XS(0)], zn = X[XS(HALF_D)];
      float k0 = z0.x, v0 = z0.y, kn = zn.x, vn = zn.y;
      float p0 = (k0 / (fabsf(k0) + EPS_)) * (v0 / (fabsf(v0) + EPS_));
      float pn = (kn / (fabsf(kn) + EPS_)) * (vn / (fabsf(vn) + EPS_));
      p = mkf2(p0, pn);
    } else {
      float2 A = X[XS(d)];
      float2 Bc = X[XS(D_DIM - d)];
      float2 Bj = mkf2(Bc.x, -Bc.y);
      float2 Fk = mkf2(0.5f * (A.x + Bj.x), 0.5f * (A.y + Bj.y));
      float2 tt = mkf2(0.5f * (A.x - Bj.x), 0.5f * (A.y - Bj.y));
      float2 Fv = mkf2(tt.y, -tt.x);
      float sa = 1.f / (sqrtf(Fk.x*Fk.x + Fk.y*Fk.y) + EPS_);
      float sb = 1.f / (sqrtf(Fv.x*Fv.x + Fv.y*Fv.y) + EPS_);
      p = cmulf(Fk, Fv);
      float sc = sa * sb;
      p.x *= sc; p.y *= sc;
    }
    outp[d] = (unsigned)f2bf(p.x) | ((unsigned)f2bf(p.y) << 16);
  }
}

// --------------------------------------------------------------- scan -----
// Spectra stored as bf16 pairs, 4 bins (16B) per thread; f32 accumulators
// and f32 chunk partials. part layout [b][chunk][1024] float2.
__global__ __launch_bounds__(256)
void scan_partial(const unsigned short* __restrict__ kvb, float2* __restrict__ part)
{
  int gid = blockIdx.x * 256 + threadIdx.x;        // 0 .. 32767
  int q4 = gid & 255;
  int chunk = (gid >> 8) & (NCHUNK - 1);
  int b = gid >> 14;
  const unsigned short* p = kvb + (size_t)(b * S_DIM + chunk * CHLEN) * 4096 + q4 * 8;
  float ar[4] = {0,0,0,0}, ai[4] = {0,0,0,0};
  for (int s = 0; s < CHLEN; ++s) {
    ushort8 v = *(const ushort8*)(p + (size_t)s * 4096);
#pragma unroll
    for (int e = 0; e < 4; ++e) { ar[e] += bf2f(v[2*e]); ai[e] += bf2f(v[2*e+1]); }
  }
  float2* pp = part + (size_t)(b * NCHUNK + chunk) * HALF_D + q4 * 4;
#pragma unroll
  for (int e = 0; e < 4; ++e) pp[e] = mkf2(ar[e], ai[e]);
}

__global__ __launch_bounds__(256)
void scan_offsets(float2* __restrict__ part)
{
  int gid = blockIdx.x * 256 + threadIdx.x;        // 0 .. B*HALF_D-1
  int d = gid & (HALF_D - 1);
  int b = gid >> 10;
  float2* p = part + (size_t)b * (NCHUNK * HALF_D) + d;
  float2 acc = mkf2(0.f, 0.f);
  for (int c = 0; c < NCHUNK; ++c) {
    float2 v = p[(size_t)c * HALF_D];
    p[(size_t)c * HALF_D] = acc;                   // exclusive prefix
    acc.x += v.x; acc.y += v.y;
  }
}

__global__ __launch_bounds__(256)
void scan_apply(unsigned short* __restrict__ kvb, const float2* __restrict__ part)
{
  int gid = blockIdx.x * 256 + threadIdx.x;
  int q4 = gid & 255;
  int chunk = (gid >> 8) & (NCHUNK - 1);
  int b = gid >> 14;
  unsigned short* p = kvb + (size_t)(b * S_DIM + chunk * CHLEN) * 4096 + q4 * 8;
  const float2* pp = part + (size_t)(b * NCHUNK + chunk) * HALF_D + q4 * 4;
  float ar[4], ai[4];
#pragma unroll
  for (int e = 0; e < 4; ++e) { float2 v = pp[e]; ar[e] = v.x; ai[e] = v.y; }
  for (int s = 0; s < CHLEN; ++s) {
    ushort8 v = *(const ushort8*)(p + (size_t)s * 4096);
    ushort8 o;
#pragma unroll
    for (int e = 0; e < 4; ++e) {
      ar[e] += bf2f(v[2*e]); ai[e] += bf2f(v[2*e+1]);
      o[2*e] = f2bf(ar[e]); o[2*e+1] = f2bf(ai[e]);
    }
    *(ushort8*)(p + (size_t)s * 4096) = o;
  }
}

// --------------------------------------------------------------- final ----
// out = base + gate * real(ifft(conj(Fq) * Fmem)); q bf16, Fmem bf16 pairs.
__global__ __launch_bounds__(256)
void final_kernel(const unsigned short* __restrict__ qb,
                  const unsigned short* __restrict__ kvb,
                  const float* __restrict__ base, const float* __restrict__ gate,
                  const float2* __restrict__ twg, float* __restrict__ out)
{
  __shared__ float2 X[D_DIM];
  __shared__ float twr[HALF_D], twi[HALF_D];
  const int t = threadIdx.x;
  const size_t row = blockIdx.x;
  const unsigned short* qrow = qb + row * 2048;
  const unsigned short* mrow = kvb + row * 4096;   // bf16 (re,im) pairs

  for (int i = t; i < HALF_D; i += 256) {
    float2 w = twg[i]; int s = TS(i); twr[s] = w.x; twi[s] = w.y;
  }
  {
    int i0 = t * 8;
    ushort8 q8 = *(const ushort8*)(qrow + i0);
#pragma unroll
    for (int r = 0; r < 8; ++r) {
      int i = i0 + r;
      int p = __brev((unsigned)i) >> 21;
      X[XS(p)] = mkf2(bf2f(q8[r]), 0.f);
    }
  }
  __syncthreads();
  fft_fwd(X, twr, twi, t);

  for (int d = t; d < HALF_D; d += 256) {
    float fmre = bf2f(mrow[2*d]), fmim = bf2f(mrow[2*d+1]);
    if (d == 0) {
      float2 f0 = X[XS(0)], f1 = X[XS(HALF_D)];
      X[XS(0)]      = mkf2(f0.x * fmre, -f0.y * fmre);
      X[XS(HALF_D)] = mkf2(f1.x * fmim, -f1.y * fmim);
    } else {
      float2 fq = X[XS(d)];
      X[XS(d)] = mkf2(fq.x*fmre + fq.y*fmim, fq.x*fmim - fq.y*fmre);
      float2 f2 = X[XS(D_DIM - d)];
      X[XS(D_DIM - d)] = mkf2(f2.x*fmre - f2.y*fmim, -f2.x*fmim - f2.y*fmre);
    }
  }
  __syncthreads();
  fft_inv(X, twr, twi, t);

  const float gv = gate[0] * (1.f / (float)D_DIM);
  const float* brow = base + row * D_DIM;
  float* orow = out + row * D_DIM;
  for (int i = t; i < D_DIM; i += 256) {
    int p = __brev((unsigned)i) >> 21;
    orow[i] = brow[i] + gv * X[XS(p)].x;
  }
}

// ------------------------------------------------------------ launcher ----
extern "C" void kernel_launch(void* const* d_in, const int* in_sizes, int n_in,
                              void* d_out, int out_size, void* d_ws, size_t ws_size,
                              hipStream_t stream)
{
  const float* hs   = (const float*)d_in[0];
  const float* base = (const float*)d_in[1];
  const float* Wq   = (const float*)d_in[2];
  const float* bq   = (const float*)d_in[3];
  const float* Wk   = (const float*)d_in[4];
  const float* bk   = (const float*)d_in[5];
  const float* Wv   = (const float*)d_in[6];
  const float* bv   = (const float*)d_in[7];
  const float* gate = (const float*)d_in[8];
  float* out  = (float*)d_out;

  // workspace layout (160.4 MB):
  //   hsb  bf16 [8192][2048]   (first 8KB reused as twiddle table post-GEMM)
  //   wqb|wkb|wvb bf16 [6144][2048] contiguous (fused weight)
  //   kvb  [8192] x 8KB rows: [k bf16 | v bf16] -> bf16 packed Fkv/Fmem
  //   qb   bf16 [8192][2048]
  //   part f32x2 [2][64][1024]
  char* ws = (char*)d_ws;
  unsigned short* hsb = (unsigned short*)ws;
  unsigned short* wqb = (unsigned short*)(ws + 33554432);
  unsigned short* wkb = wqb + (size_t)D_DIM * D_DIM;
  unsigned short* wvb = wkb + (size_t)D_DIM * D_DIM;
  unsigned short* kvb = (unsigned short*)(ws + 58720256);
  unsigned short* qb  = (unsigned short*)(ws + 58720256 + 67108864);
  float2* part = (float2*)(ws + 58720256 + 67108864 + 33554432);
  float2* twg  = (float2*)ws;   // overwrites hsb AFTER the GEMM consumed it

  {
    int n8 = (NROW * D_DIM) / 8;
    cvt_f32_bf16<<<n8 / 256, 256, 0, stream>>>(hs, hsb, n8);
    int w8 = (D_DIM * D_DIM) / 8;
    cvt_f32_bf16<<<w8 / 256, 256, 0, stream>>>(Wq, wqb, w8);
    cvt_f32_bf16<<<w8 / 256, 256, 0, stream>>>(Wk, wkb, w8);
    cvt_f32_bf16<<<w8 / 256, 256, 0, stream>>>(Wv, wvb, w8);
  }

  gemm_fused<<<1536, 256, 0, stream>>>(hsb, wqb, bq, bk, bv, qb, kvb);

  twiddle_init<<<4, 256, 0, stream>>>(twg);

  fftkv_kernel<<<NROW, 256, 0, stream>>>(kvb, twg);

  scan_partial<<<128, 256, 0, stream>>>(kvb, part);
  scan_offsets<<<(B_DIM * HALF_D) / 256, 256, 0, stream>>>(part);
  scan_apply<<<128, 256, 0, stream>>>(kvb, part);

  final_kernel<<<NROW, 256, 0, stream>>>(qb, kvb, base, gate, twg, out);
}

// Round 7
// 376.351 us; speedup vs baseline: 8.0349x; 1.0745x over previous
//
#include <hip/hip_runtime.h>
#include <math.h>

constexpr int D_DIM  = 2048;   // feature dim (FFT length)
constexpr int HALF_D = 1024;
constexpr int B_DIM  = 2;
constexpr int S_DIM  = 4096;
constexpr int NROW   = B_DIM * S_DIM;      // 8192
constexpr int NCHUNK = 64;                 // scan chunks along S
constexpr int CHLEN  = S_DIM / NCHUNK;     // 64
constexpr float EPS_ = 1e-8f;

typedef __attribute__((ext_vector_type(8))) short  short8;   // bf16x8 frag
typedef __attribute__((ext_vector_type(8))) unsigned short ushort8;
typedef __attribute__((ext_vector_type(4))) float  f32x4;    // MFMA acc

__device__ __forceinline__ float2 mkf2(float x, float y){ float2 r; r.x=x; r.y=y; return r; }
__device__ __forceinline__ float2 cmulf(float2 a, float2 b){
  return mkf2(fmaf(a.x, b.x, -a.y*b.y), fmaf(a.x, b.y, a.y*b.x));
}
__device__ __forceinline__ unsigned short f2bf(float x){
  unsigned u = __float_as_uint(x);
  u += 0x7fff + ((u >> 16) & 1);           // round-to-nearest-even
  return (unsigned short)(u >> 16);
}
__device__ __forceinline__ float bf2f(unsigned short h){
  return __uint_as_float(((unsigned)h) << 16);
}

// ------------------------------------------------------------ fp32→bf16 ---
__global__ __launch_bounds__(256)
void cvt_f32_bf16(const float* __restrict__ in, unsigned short* __restrict__ out, int n8)
{
  int i = blockIdx.x * 256 + threadIdx.x;
  if (i >= n8) return;
  const float4* p = (const float4*)in + (size_t)i * 2;
  float4 a = p[0], b = p[1];
  ushort8 o;
  o[0]=f2bf(a.x); o[1]=f2bf(a.y); o[2]=f2bf(a.z); o[3]=f2bf(a.w);
  o[4]=f2bf(b.x); o[5]=f2bf(b.y); o[6]=f2bf(b.z); o[7]=f2bf(b.w);
  *(ushort8*)(out + (size_t)i * 8) = o;
}

// -------------- fused q/k/v 256x256 MFMA GEMM, 8-phase schedule (m201) ----
// A [8192][2048] bf16, Wc [6144][2048] bf16 (Wq|Wk|Wv rows concatenated).
// C = A @ Wc^T + bias; q -> bf16 qb, k/v -> bf16 interleaved kvb rows.
// 8 waves (2Mx4N), per-wave 128x64 out, BK=64, 2 K-tiles / 8 phases per
// iteration, dead-region half-tile staging, vmcnt(4) only at phases 3/7,
// 8-chunk XOR LDS swizzle (conflict-free), setprio around MFMA clusters.
__global__ __launch_bounds__(512, 2)
void gemm_fused(const unsigned short* __restrict__ A,
                const unsigned short* __restrict__ Wc,
                const float* __restrict__ bq, const float* __restrict__ bk,
                const float* __restrict__ bv,
                unsigned short* __restrict__ qb, unsigned short* __restrict__ kvb)
{
  constexpr int K = 2048, NITER = 16;             // 32 K-tiles, 2/iter
  __shared__ unsigned short lds[65536];           // 128 KB: A[2][16K] B[2][16K]
  const int tid  = threadIdx.x;
  const int wid  = tid >> 6, lane = tid & 63;
  const int wr   = wid >> 2, wc = wid & 3;

  // XCD-bijective swizzle: 768 blocks = 96 per XCD; chunk = 4 M x 24 N
  int bid = blockIdx.x;
  int sw  = (bid & 7) * 96 + (bid >> 3);
  const int bm = (sw / 24) * 256, bn = (sw % 24) * 256;

  // staging coords: one gload covers 64 rows x 64 k (8 KB); lane row tid>>3,
  // stored chunk tid&7 holds global k-chunk (tid&7)^(row&7)  (8 elem chunks)
  const int srow = tid >> 3;                       // 0..63
  const int skc  = ((tid & 7) ^ (srow & 7)) * 8;
  const unsigned short* Ag = A  + (size_t)(bm + srow) * K + skc;
  const unsigned short* Bg = Wc + (size_t)(bn + srow) * K + skc;
  unsigned short* Al = lds;
  unsigned short* Bl = lds + 32768;
  const int stoff = wid * 512;                     // wave-uniform dest

  auto stA = [&](int kt, int d, int h, int r) {
    __builtin_amdgcn_global_load_lds(
      (const __attribute__((address_space(1))) void*)(Ag + (size_t)(h * 128 + r * 64) * K + kt * 64),
      (__attribute__((address_space(3))) void*)(Al + d * 16384 + h * 8192 + r * 4096 + stoff),
      16, 0, 0);
  };
  auto stB = [&](int kt, int d, int h, int r) {
    __builtin_amdgcn_global_load_lds(
      (const __attribute__((address_space(1))) void*)(Bg + (size_t)(h * 128 + r * 64) * K + kt * 64),
      (__attribute__((address_space(3))) void*)(Bl + d * 16384 + h * 8192 + r * 4096 + stoff),
      16, 0, 0);
  };

  // fragment read coords: row stride 64 ushorts; k-chunk XOR-swizzled by row
  const int frow = lane & 15;
  const int kq   = lane >> 4;                      // 0..3
  int ksw[2];
  ksw[0] = ((0 * 4 + kq) ^ (frow & 7)) * 8;
  ksw[1] = ((1 * 4 + kq) ^ (frow & 7)) * 8;
  const int arow0 = (wr * 128 + frow) * 64;        // + mf*1024 + ksw[ks]
  const int brow0 = (wc * 64 + frow) * 64;         // + nf*1024 + ksw[ks]

  f32x4 acc[8][4];
#pragma unroll
  for (int i = 0; i < 8; ++i)
#pragma unroll
    for (int j = 0; j < 4; ++j) acc[i][j] = (f32x4){0.f, 0.f, 0.f, 0.f};

  // prologue: A(0),B(0) -> dbuf0; B(1) -> dbuf1.B  (A(1) staged at P0/P1)
  stA(0, 0, 0, 0); stA(0, 0, 0, 1); stA(0, 0, 1, 0); stA(0, 0, 1, 1);
  stB(0, 0, 0, 0); stB(0, 0, 0, 1); stB(0, 0, 1, 0); stB(0, 0, 1, 1);
  stB(1, 1, 0, 0); stB(1, 1, 0, 1); stB(1, 1, 1, 0); stB(1, 1, 1, 1);
  asm volatile("s_waitcnt vmcnt(4)" ::: "memory");
  __builtin_amdgcn_s_barrier();
  __builtin_amdgcn_sched_barrier(0);

#pragma unroll 1
  for (int it = 0; it < NITER; ++it) {
    const bool nl = (it < NITER - 1);
    const int t1 = 2 * it + 1;
    short8 bfr[8];
#pragma unroll
    for (int ph = 0; ph < 8; ++ph) {
      const int g  = ph & 3;
      const int db = ph >> 2;                      // dbuf being computed
      const unsigned short* Ab = Al + db * 16384;
      const unsigned short* Bb = Bl + db * 16384;

      // --- stage one half-tile (dead-region schedule) ---
      if      (ph == 0) { stA(t1, 1, 0, 0); stA(t1, 1, 0, 1); }
      else if (ph == 1) { stA(t1, 1, 1, 0); stA(t1, 1, 1, 1); }
      else if (ph == 2) { if (nl) { stB(t1 + 1, 0, 0, 0); stB(t1 + 1, 0, 0, 1); } }
      else if (ph == 3) { if (nl) { stB(t1 + 1, 0, 1, 0); stB(t1 + 1, 0, 1, 1); } }
      else if (ph == 4) { if (nl) { stA(t1 + 1, 0, 0, 0); stA(t1 + 1, 0, 0, 1); } }
      else if (ph == 5) { if (nl) { stA(t1 + 1, 0, 1, 0); stA(t1 + 1, 0, 1, 1); } }
      else if (ph == 6) { if (nl) { stB(t1 + 2, 1, 0, 0); stB(t1 + 2, 1, 0, 1); } }
      else              { if (nl) { stB(t1 + 2, 1, 1, 0); stB(t1 + 2, 1, 1, 1); } }

      // --- ds reads: A quadrant every phase; B once per K-tile ---
      short8 af[2][2];
#pragma unroll
      for (int q = 0; q < 2; ++q)
#pragma unroll
        for (int ks = 0; ks < 2; ++ks)
          af[q][ks] = *(const short8*)(Ab + arow0 + (2 * g + q) * 1024 + ksw[ks]);
      if (g == 0) {
#pragma unroll
        for (int nf = 0; nf < 4; ++nf)
#pragma unroll
          for (int ks = 0; ks < 2; ++ks)
            bfr[nf * 2 + ks] = *(const short8*)(Bb + brow0 + nf * 1024 + ksw[ks]);
      }

      __builtin_amdgcn_s_barrier();
      asm volatile("s_waitcnt lgkmcnt(0)" ::: "memory");
      __builtin_amdgcn_sched_barrier(0);
      __builtin_amdgcn_s_setprio(1);
#pragma unroll
      for (int ks = 0; ks < 2; ++ks)
#pragma unroll
        for (int q = 0; q < 2; ++q)
#pragma unroll
          for (int nf = 0; nf < 4; ++nf)
            acc[2 * g + q][nf] = __builtin_amdgcn_mfma_f32_16x16x32_bf16(
                af[q][ks], bfr[nf * 2 + ks], acc[2 * g + q][nf], 0, 0, 0);
      __builtin_amdgcn_s_setprio(0);

      if (ph == 3) {
        if (nl) asm volatile("s_waitcnt vmcnt(4)" ::: "memory");
        else    asm volatile("s_waitcnt vmcnt(0)" ::: "memory");
      } else if (ph == 7) {
        if (nl) asm volatile("s_waitcnt vmcnt(4)" ::: "memory");
      }
      __builtin_amdgcn_s_barrier();
    }
  }

  // ---- epilogue: route by segment; all outputs bf16
  const int seg = bn >> 11;                        // 0:q 1:k 2:v
  const float* bp = (seg == 0) ? bq : (seg == 1) ? bk : bv;
  float bias_j[4];
#pragma unroll
  for (int j = 0; j < 4; ++j)
    bias_j[j] = bp[(bn + wc * 64 + j * 16 + frow) & 2047];
  const int er = (lane >> 4) * 4;
  unsigned short* dst = (seg == 0) ? qb : kvb;
  const size_t rstride = (seg == 0) ? 2048 : 4096;
  const int coff = (seg == 2) ? 2048 : 0;
#pragma unroll
  for (int I = 0; I < 8; ++I) {
    int row = bm + wr * 128 + I * 16 + er;
#pragma unroll
    for (int j = 0; j < 4; ++j) {
      int col = (bn + wc * 64 + j * 16 + frow) & 2047;
#pragma unroll
      for (int r = 0; r < 4; ++r) {
        float val = acc[I][j][r] + bias_j[j];
        dst[(size_t)(row + r) * rstride + coff + col] = f2bf(val);
      }
    }
  }
}

// ------------------------------------------------------------- FFT core ---
// 2048-pt FFT, 256 threads, radix 8-8-8-4 macro-stages, register butterflies.
__device__ __forceinline__ int XS(int i){ return i ^ (((i >> 5) ^ (i >> 10)) & 31); }
__device__ __forceinline__ int TS(int i){ return i ^ ((i >> 5) & 31); }

__device__ __forceinline__ float2 mulmi(float2 w){ return mkf2(w.y, -w.x); }   // w * (-i)
__device__ __forceinline__ float2 mulw8(float2 w){                              // w * e^{-i pi/4}
  const float c = 0.70710678118654752f;
  return mkf2(c * (w.x + w.y), c * (w.y - w.x));
}
__device__ __forceinline__ void bfly(float2& a, float2& b, float2 w){
  float2 v = cmulf(w, b);
  b = mkf2(a.x - v.x, a.y - v.y);
  a = mkf2(a.x + v.x, a.y + v.y);
}
__device__ __forceinline__ void bflyc(float2& a, float2& b, float2 w){
  float2 d = mkf2(a.x - b.x, a.y - b.y);
  a = mkf2(a.x + b.x, a.y + b.y);
  b = mkf2(fmaf(d.x, w.x, d.y * w.y), fmaf(d.y, w.x, -d.x * w.y));  // d * conj(w)
}

__device__ __forceinline__ void fwd8(float2 e[8], float2 wA, float2 wB0, float2 wC0){
  bfly(e[0], e[1], wA); bfly(e[2], e[3], wA); bfly(e[4], e[5], wA); bfly(e[6], e[7], wA);
  float2 wB1 = mulmi(wB0);
  bfly(e[0], e[2], wB0); bfly(e[1], e[3], wB1); bfly(e[4], e[6], wB0); bfly(e[5], e[7], wB1);
  float2 wC1 = mulw8(wC0), wC2 = mulmi(wC0), wC3 = mulmi(wC1);
  bfly(e[0], e[4], wC0); bfly(e[1], e[5], wC1); bfly(e[2], e[6], wC2); bfly(e[3], e[7], wC3);
}
__device__ __forceinline__ void inv8(float2 e[8], float2 wA, float2 wB0, float2 wC0){
  float2 wC1 = mulw8(wC0), wC2 = mulmi(wC0), wC3 = mulmi(wC1);
  bflyc(e[0], e[4], wC0); bflyc(e[1], e[5], wC1); bflyc(e[2], e[6], wC2); bflyc(e[3], e[7], wC3);
  float2 wB1 = mulmi(wB0);
  bflyc(e[0], e[2], wB0); bflyc(e[1], e[3], wB1); bflyc(e[4], e[6], wB0); bflyc(e[5], e[7], wB1);
  bflyc(e[0], e[1], wA); bflyc(e[2], e[3], wA); bflyc(e[4], e[5], wA); bflyc(e[6], e[7], wA);
}

__device__ __forceinline__ float2 twld(const float* twr, const float* twi, int i){
  int s = TS(i);
  return mkf2(twr[s], twi[s]);
}

__device__ void fft_fwd(float2* X, const float* twr, const float* twi, int t)
{
  const float2 one = mkf2(1.f, 0.f);
  {                                   // MS1
    int b = 8 * t;
    float2 e[8];
#pragma unroll
    for (int r = 0; r < 8; ++r) e[r] = X[XS(b + r)];
    fwd8(e, one, one, one);
#pragma unroll
    for (int r = 0; r < 8; ++r) X[XS(b + r)] = e[r];
  }
  __syncthreads();
  {                                   // MS2
    int u = t >> 5, b = 64 * (t & 31) + u;
    float2 e[8];
#pragma unroll
    for (int r = 0; r < 8; ++r) e[r] = X[XS(b + 8 * r)];
    fwd8(e, twld(twr,twi,128*u), twld(twr,twi,64*u), twld(twr,twi,32*u));
#pragma unroll
    for (int r = 0; r < 8; ++r) X[XS(b + 8 * r)] = e[r];
  }
  __syncthreads();
  {                                   // MS3
    int u = t & 63, b = 512 * (t >> 6) + u;
    float2 e[8];
#pragma unroll
    for (int r = 0; r < 8; ++r) e[r] = X[XS(b + 64 * r)];
    fwd8(e, twld(twr,twi,16*u), twld(twr,twi,8*u), twld(twr,twi,4*u));
#pragma unroll
    for (int r = 0; r < 8; ++r) X[XS(b + 64 * r)] = e[r];
  }
  __syncthreads();
#pragma unroll
  for (int h = 0; h < 2; ++h) {       // MS4: radix-4
    int u = t + 256 * h;
    float2 f[4];
#pragma unroll
    for (int r = 0; r < 4; ++r) f[r] = X[XS(u + 512 * r)];
    float2 wA = twld(twr,twi,2*u), wB0 = twld(twr,twi,u), wB1 = mulmi(wB0);
    bfly(f[0], f[1], wA);  bfly(f[2], f[3], wA);
    bfly(f[0], f[2], wB0); bfly(f[1], f[3], wB1);
#pragma unroll
    for (int r = 0; r < 4; ++r) X[XS(u + 512 * r)] = f[r];
  }
  __syncthreads();
}

__device__ void fft_inv(float2* X, const float* twr, const float* twi, int t)
{
  const float2 one = mkf2(1.f, 0.f);
#pragma unroll
  for (int h = 0; h < 2; ++h) {       // MS4'
    int u = t + 256 * h;
    float2 f[4];
#pragma unroll
    for (int r = 0; r < 4; ++r) f[r] = X[XS(u + 512 * r)];
    float2 wA = twld(twr,twi,2*u), wB0 = twld(twr,twi,u), wB1 = mulmi(wB0);
    bflyc(f[0], f[2], wB0); bflyc(f[1], f[3], wB1);
    bflyc(f[0], f[1], wA);  bflyc(f[2], f[3], wA);
#pragma unroll
    for (int r = 0; r < 4; ++r) X[XS(u + 512 * r)] = f[r];
  }
  __syncthreads();
  {                                   // MS3'
    int u = t & 63, b = 512 * (t >> 6) + u;
    float2 e[8];
#pragma unroll
    for (int r = 0; r < 8; ++r) e[r] = X[XS(b + 64 * r)];
    inv8(e, twld(twr,twi,16*u), twld(twr,twi,8*u), twld(twr,twi,4*u));
#pragma unroll
    for (int r = 0; r < 8; ++r) X[XS(b + 64 * r)] = e[r];
  }
  __syncthreads();
  {                                   // MS2'
    int u = t >> 5, b = 64 * (t & 31) + u;
    float2 e[8];
#pragma unroll
    for (int r = 0; r < 8; ++r) e[r] = X[XS(b + 8 * r)];
    inv8(e, twld(twr,twi,128*u), twld(twr,twi,64*u), twld(twr,twi,32*u));
#pragma unroll
    for (int r = 0; r < 8; ++r) X[XS(b + 8 * r)] = e[r];
  }
  __syncthreads();
  {                                   // MS1'
    int b = 8 * t;
    float2 e[8];
#pragma unroll
    for (int r = 0; r < 8; ++r) e[r] = X[XS(b + r)];
    inv8(e, one, one, one);
#pragma unroll
    for (int r = 0; r < 8; ++r) X[XS(b + r)] = e[r];
  }
  __syncthreads();
}

// ------------------------------------------------------- twiddle table ----
__global__ __launch_bounds__(256)
void twiddle_init(float2* __restrict__ twg)
{
  int i = blockIdx.x * 256 + threadIdx.x;
  if (i < HALF_D) {
    float sv, cv;
    sincosf(-6.283185307179586f * (float)i / (float)D_DIM, &sv, &cv);
    twg[i] = mkf2(cv, sv);
  }
}

// ---------------------------------------------------------- FFT(k,v)·mul --
// kvb row r: [k bf16 x2048 | v bf16 x2048]. One complex FFT of (k + i·v)
// recovers both spectra; writes packed half-spectrum of unit(Fk)·unit(Fv)
// as bf16 pairs (re,im) into the first 2048 ushorts of the row slot.
__global__ __launch_bounds__(256)
void fftkv_kernel(unsigned short* __restrict__ kvb, const float2* __restrict__ twg)
{
  __shared__ float2 X[D_DIM];
  __shared__ float twr[HALF_D], twi[HALF_D];
  const int t = threadIdx.x;
  const size_t row = blockIdx.x;
  const unsigned short* kvrow = kvb + row * 4096;

  for (int i = t; i < HALF_D; i += 256) {
    float2 w = twg[i]; int s = TS(i); twr[s] = w.x; twi[s] = w.y;
  }
  {
    int i0 = t * 8;
    ushort8 k8 = *(const ushort8*)(kvrow + i0);
    ushort8 v8 = *(const ushort8*)(kvrow + 2048 + i0);
#pragma unroll
    for (int r = 0; r < 8; ++r) {
      int i = i0 + r;
      int p = __brev((unsigned)i) >> 21;
      X[XS(p)] = mkf2(bf2f(k8[r]), bf2f(v8[r]));
    }
  }
  __syncthreads();
  fft_fwd(X, twr, twi, t);

  unsigned int* outp = (unsigned int*)(kvb + row * 4096);
  for (int d = t; d < HALF_D; d += 256) {
    float2 p;
    if (d == 0) {
      float2 z0 = X[XS(0)], zn = X[XS(HALF_D)];
      float k0 = z0.x, v0 = z0.y, kn = zn.x, vn = zn.y;
      float p0 = (k0 / (fabsf(k0) + EPS_)) * (v0 / (fabsf(v0) + EPS_));
      float pn = (kn / (fabsf(kn) + EPS_)) * (vn / (fabsf(vn) + EPS_));
      p = mkf2(p0, pn);
    } else {
      float2 A = X[XS(d)];
      float2 Bc = X[XS(D_DIM - d)];
      float2 Bj = mkf2(Bc.x, -Bc.y);
      float2 Fk = mkf2(0.5f * (A.x + Bj.x), 0.5f * (A.y + Bj.y));
      float2 tt = mkf2(0.5f * (A.x - Bj.x), 0.5f * (A.y - Bj.y));
      float2 Fv = mkf2(tt.y, -tt.x);
      float sa = 1.f / (sqrtf(Fk.x*Fk.x + Fk.y*Fk.y) + EPS_);
      float sb = 1.f / (sqrtf(Fv.x*Fv.x + Fv.y*Fv.y) + EPS_);
      p = cmulf(Fk, Fv);
      float sc = sa * sb;
      p.x *= sc; p.y *= sc;
    }
    outp[d] = (unsigned)f2bf(p.x) | ((unsigned)f2bf(p.y) << 16);
  }
}

// --------------------------------------------------------------- scan -----
// Spectra stored as bf16 pairs, 4 bins (16B) per thread; f32 accumulators
// and f32 chunk partials. part layout [b][chunk][1024] float2.
__global__ __launch_bounds__(256)
void scan_partial(const unsigned short* __restrict__ kvb, float2* __restrict__ part)
{
  int gid = blockIdx.x * 256 + threadIdx.x;        // 0 .. 32767
  int q4 = gid & 255;
  int chunk = (gid >> 8) & (NCHUNK - 1);
  int b = gid >> 14;
  const unsigned short* p = kvb + (size_t)(b * S_DIM + chunk * CHLEN) * 4096 + q4 * 8;
  float ar[4] = {0,0,0,0}, ai[4] = {0,0,0,0};
  for (int s = 0; s < CHLEN; ++s) {
    ushort8 v = *(const ushort8*)(p + (size_t)s * 4096);
#pragma unroll
    for (int e = 0; e < 4; ++e) { ar[e] += bf2f(v[2*e]); ai[e] += bf2f(v[2*e+1]); }
  }
  float2* pp = part + (size_t)(b * NCHUNK + chunk) * HALF_D + q4 * 4;
#pragma unroll
  for (int e = 0; e < 4; ++e) pp[e] = mkf2(ar[e], ai[e]);
}

__global__ __launch_bounds__(256)
void scan_offsets(float2* __restrict__ part)
{
  int gid = blockIdx.x * 256 + threadIdx.x;        // 0 .. B*HALF_D-1
  int d = gid & (HALF_D - 1);
  int b = gid >> 10;
  float2* p = part + (size_t)b * (NCHUNK * HALF_D) + d;
  float2 acc = mkf2(0.f, 0.f);
  for (int c = 0; c < NCHUNK; ++c) {
    float2 v = p[(size_t)c * HALF_D];
    p[(size_t)c * HALF_D] = acc;                   // exclusive prefix
    acc.x += v.x; acc.y += v.y;
  }
}

__global__ __launch_bounds__(256)
void scan_apply(unsigned short* __restrict__ kvb, const float2* __restrict__ part)
{
  int gid = blockIdx.x * 256 + threadIdx.x;
  int q4 = gid & 255;
  int chunk = (gid >> 8) & (NCHUNK - 1);
  int b = gid >> 14;
  unsigned short* p = kvb + (size_t)(b * S_DIM + chunk * CHLEN) * 4096 + q4 * 8;
  const float2* pp = part + (size_t)(b * NCHUNK + chunk) * HALF_D + q4 * 4;
  float ar[4], ai[4];
#pragma unroll
  for (int e = 0; e < 4; ++e) { float2 v = pp[e]; ar[e] = v.x; ai[e] = v.y; }
  for (int s = 0; s < CHLEN; ++s) {
    ushort8 v = *(const ushort8*)(p + (size_t)s * 4096);
    ushort8 o;
#pragma unroll
    for (int e = 0; e < 4; ++e) {
      ar[e] += bf2f(v[2*e]); ai[e] += bf2f(v[2*e+1]);
      o[2*e] = f2bf(ar[e]); o[2*e+1] = f2bf(ai[e]);
    }
    *(ushort8*)(p + (size_t)s * 4096) = o;
  }
}

// --------------------------------------------------------------- final ----
// out = base + gate * real(ifft(conj(Fq) * Fmem)); q bf16, Fmem bf16 pairs.
__global__ __launch_bounds__(256)
void final_kernel(const unsigned short* __restrict__ qb,
                  const unsigned short* __restrict__ kvb,
                  const float* __restrict__ base, const float* __restrict__ gate,
                  const float2* __restrict__ twg, float* __restrict__ out)
{
  __shared__ float2 X[D_DIM];
  __shared__ float twr[HALF_D], twi[HALF_D];
  const int t = threadIdx.x;
  const size_t row = blockIdx.x;
  const unsigned short* qrow = qb + row * 2048;
  const unsigned short* mrow = kvb + row * 4096;   // bf16 (re,im) pairs

  for (int i = t; i < HALF_D; i += 256) {
    float2 w = twg[i]; int s = TS(i); twr[s] = w.x; twi[s] = w.y;
  }
  {
    int i0 = t * 8;
    ushort8 q8 = *(const ushort8*)(qrow + i0);
#pragma unroll
    for (int r = 0; r < 8; ++r) {
      int i = i0 + r;
      int p = __brev((unsigned)i) >> 21;
      X[XS(p)] = mkf2(bf2f(q8[r]), 0.f);
    }
  }
  __syncthreads();
  fft_fwd(X, twr, twi, t);

  for (int d = t; d < HALF_D; d += 256) {
    float fmre = bf2f(mrow[2*d]), fmim = bf2f(mrow[2*d+1]);
    if (d == 0) {
      float2 f0 = X[XS(0)], f1 = X[XS(HALF_D)];
      X[XS(0)]      = mkf2(f0.x * fmre, -f0.y * fmre);
      X[XS(HALF_D)] = mkf2(f1.x * fmim, -f1.y * fmim);
    } else {
      float2 fq = X[XS(d)];
      X[XS(d)] = mkf2(fq.x*fmre + fq.y*fmim, fq.x*fmim - fq.y*fmre);
      float2 f2 = X[XS(D_DIM - d)];
      X[XS(D_DIM - d)] = mkf2(f2.x*fmre - f2.y*fmim, -f2.x*fmim - f2.y*fmre);
    }
  }
  __syncthreads();
  fft_inv(X, twr, twi, t);

  const float gv = gate[0] * (1.f / (float)D_DIM);
  const float* brow = base + row * D_DIM;
  float* orow = out + row * D_DIM;
  for (int i = t; i < D_DIM; i += 256) {
    int p = __brev((unsigned)i) >> 21;
    orow[i] = brow[i] + gv * X[XS(p)].x;
  }
}

// ------------------------------------------------------------ launcher ----
extern "C" void kernel_launch(void* const* d_in, const int* in_sizes, int n_in,
                              void* d_out, int out_size, void* d_ws, size_t ws_size,
                              hipStream_t stream)
{
  const float* hs   = (const float*)d_in[0];
  const float* base = (const float*)d_in[1];
  const float* Wq   = (const float*)d_in[2];
  const float* bq   = (const float*)d_in[3];
  const float* Wk   = (const float*)d_in[4];
  const float* bk   = (const float*)d_in[5];
  const float* Wv   = (const float*)d_in[6];
  const float* bv   = (const float*)d_in[7];
  const float* gate = (const float*)d_in[8];
  float* out  = (float*)d_out;

  // workspace layout:
  //   hsb  bf16 [8192][2048]   (first 8KB reused as twiddle table post-GEMM)
  //   wqb|wkb|wvb bf16 [6144][2048] contiguous (fused weight)
  //   kvb  [8192] x 8KB rows: [k bf16 | v bf16] -> bf16 packed Fkv/Fmem
  //   qb   bf16 [8192][2048]
  //   part f32x2 [2][64][1024]
  char* ws = (char*)d_ws;
  unsigned short* hsb = (unsigned short*)ws;
  unsigned short* wqb = (unsigned short*)(ws + 33554432);
  unsigned short* wkb = wqb + (size_t)D_DIM * D_DIM;
  unsigned short* wvb = wkb + (size_t)D_DIM * D_DIM;
  unsigned short* kvb = (unsigned short*)(ws + 58720256);
  unsigned short* qb  = (unsigned short*)(ws + 58720256 + 67108864);
  float2* part = (float2*)(ws + 58720256 + 67108864 + 33554432);
  float2* twg  = (float2*)ws;   // overwrites hsb AFTER the GEMM consumed it

  {
    int n8 = (NROW * D_DIM) / 8;
    cvt_f32_bf16<<<n8 / 256, 256, 0, stream>>>(hs, hsb, n8);
    int w8 = (D_DIM * D_DIM) / 8;
    cvt_f32_bf16<<<w8 / 256, 256, 0, stream>>>(Wq, wqb, w8);
    cvt_f32_bf16<<<w8 / 256, 256, 0, stream>>>(Wk, wkb, w8);
    cvt_f32_bf16<<<w8 / 256, 256, 0, stream>>>(Wv, wvb, w8);
  }

  gemm_fused<<<768, 512, 0, stream>>>(hsb, wqb, bq, bk, bv, qb, kvb);

  twiddle_init<<<4, 256, 0, stream>>>(twg);

  fftkv_kernel<<<NROW, 256, 0, stream>>>(kvb, twg);

  scan_partial<<<128, 256, 0, stream>>>(kvb, part);
  scan_offsets<<<(B_DIM * HALF_D) / 256, 256, 0, stream>>>(part);
  scan_apply<<<128, 256, 0, stream>>>(kvb, part);

  final_kernel<<<NROW, 256, 0, stream>>>(qb, kvb, base, gate, twg, out);
}

// Round 8
// 351.042 us; speedup vs baseline: 8.6142x; 1.0721x over previous
//
#include <hip/hip_runtime.h>
#include <math.h>

constexpr int D_DIM  = 2048;   // feature dim (FFT length)
constexpr int HALF_D = 1024;
constexpr int B_DIM  = 2;
constexpr int S_DIM  = 4096;
constexpr int NROW   = B_DIM * S_DIM;      // 8192
constexpr int NCHUNK = 64;                 // scan chunks along S
constexpr int CHLEN  = S_DIM / NCHUNK;     // 64
constexpr float EPS_ = 1e-8f;

typedef __attribute__((ext_vector_type(8))) short  short8;   // bf16x8 frag
typedef __attribute__((ext_vector_type(8))) unsigned short ushort8;
typedef __attribute__((ext_vector_type(4))) float  f32x4;    // MFMA acc

__device__ __forceinline__ float2 mkf2(float x, float y){ float2 r; r.x=x; r.y=y; return r; }
__device__ __forceinline__ float2 cmulf(float2 a, float2 b){
  return mkf2(fmaf(a.x, b.x, -a.y*b.y), fmaf(a.x, b.y, a.y*b.x));
}
__device__ __forceinline__ unsigned short f2bf(float x){
  unsigned u = __float_as_uint(x);
  u += 0x7fff + ((u >> 16) & 1);           // round-to-nearest-even
  return (unsigned short)(u >> 16);
}
__device__ __forceinline__ float bf2f(unsigned short h){
  return __uint_as_float(((unsigned)h) << 16);
}

// ----------------------------------------------- fp32→bf16 (all inputs) ---
// i in [0, n8): hs -> hsb.  i in [n8, n8+3*w8): Wq|Wk|Wv -> wb (contiguous).
__global__ __launch_bounds__(256)
void cvt_inputs(const float* __restrict__ hs, const float* __restrict__ Wq,
                const float* __restrict__ Wk, const float* __restrict__ Wv,
                unsigned short* __restrict__ hsb, unsigned short* __restrict__ wb)
{
  constexpr int n8 = (NROW * D_DIM) / 8;          // 2097152
  constexpr int w8 = (D_DIM * D_DIM) / 8;         // 524288
  int i = blockIdx.x * 256 + threadIdx.x;
  const float* src;
  unsigned short* dst;
  int local;
  if (i < n8) { src = hs; local = i; dst = hsb + (size_t)i * 8; }
  else {
    int j = i - n8;
    int seg = j >> 19;                            // j / w8
    local = j & (w8 - 1);
    src = (seg == 0) ? Wq : (seg == 1) ? Wk : Wv;
    dst = wb + (size_t)j * 8;
  }
  const float4* p = (const float4*)src + (size_t)local * 2;
  float4 a = p[0], b = p[1];
  ushort8 o;
  o[0]=f2bf(a.x); o[1]=f2bf(a.y); o[2]=f2bf(a.z); o[3]=f2bf(a.w);
  o[4]=f2bf(b.x); o[5]=f2bf(b.y); o[6]=f2bf(b.z); o[7]=f2bf(b.w);
  *(ushort8*)dst = o;
}

// -------------- fused q/k/v 256x256 MFMA GEMM, 8-phase schedule (m201) ----
// A [8192][2048] bf16, Wc [6144][2048] bf16 (Wq|Wk|Wv rows concatenated).
// C = A @ Wc^T + bias; q -> bf16 qb, k/v -> bf16 interleaved kvb rows.
// 8 waves (2Mx4N), per-wave 128x64 out, BK=64, 2 K-tiles / 8 phases per
// iteration, dead-region half-tile staging, vmcnt(4) only at phases 3/7,
// 8-chunk XOR LDS swizzle (conflict-free), setprio around MFMA clusters.
__global__ __launch_bounds__(512, 2)
void gemm_fused(const unsigned short* __restrict__ A,
                const unsigned short* __restrict__ Wc,
                const float* __restrict__ bq, const float* __restrict__ bk,
                const float* __restrict__ bv,
                unsigned short* __restrict__ qb, unsigned short* __restrict__ kvb)
{
  constexpr int K = 2048, NITER = 16;             // 32 K-tiles, 2/iter
  __shared__ unsigned short lds[65536];           // 128 KB: A[2][16K] B[2][16K]
  const int tid  = threadIdx.x;
  const int wid  = tid >> 6, lane = tid & 63;
  const int wr   = wid >> 2, wc = wid & 3;

  // XCD-bijective swizzle: 768 blocks = 96 per XCD; chunk = 4 M x 24 N
  int bid = blockIdx.x;
  int sw  = (bid & 7) * 96 + (bid >> 3);
  const int bm = (sw / 24) * 256, bn = (sw % 24) * 256;

  // staging coords: one gload covers 64 rows x 64 k (8 KB); lane row tid>>3,
  // stored chunk tid&7 holds global k-chunk (tid&7)^(row&7)  (8 elem chunks)
  const int srow = tid >> 3;                       // 0..63
  const int skc  = ((tid & 7) ^ (srow & 7)) * 8;
  const unsigned short* Ag = A  + (size_t)(bm + srow) * K + skc;
  const unsigned short* Bg = Wc + (size_t)(bn + srow) * K + skc;
  unsigned short* Al = lds;
  unsigned short* Bl = lds + 32768;
  const int stoff = wid * 512;                     // wave-uniform dest

  auto stA = [&](int kt, int d, int h, int r) {
    __builtin_amdgcn_global_load_lds(
      (const __attribute__((address_space(1))) void*)(Ag + (size_t)(h * 128 + r * 64) * K + kt * 64),
      (__attribute__((address_space(3))) void*)(Al + d * 16384 + h * 8192 + r * 4096 + stoff),
      16, 0, 0);
  };
  auto stB = [&](int kt, int d, int h, int r) {
    __builtin_amdgcn_global_load_lds(
      (const __attribute__((address_space(1))) void*)(Bg + (size_t)(h * 128 + r * 64) * K + kt * 64),
      (__attribute__((address_space(3))) void*)(Bl + d * 16384 + h * 8192 + r * 4096 + stoff),
      16, 0, 0);
  };

  // fragment read coords: row stride 64 ushorts; k-chunk XOR-swizzled by row
  const int frow = lane & 15;
  const int kq   = lane >> 4;                      // 0..3
  int ksw[2];
  ksw[0] = ((0 * 4 + kq) ^ (frow & 7)) * 8;
  ksw[1] = ((1 * 4 + kq) ^ (frow & 7)) * 8;
  const int arow0 = (wr * 128 + frow) * 64;        // + mf*1024 + ksw[ks]
  const int brow0 = (wc * 64 + frow) * 64;         // + nf*1024 + ksw[ks]

  f32x4 acc[8][4];
#pragma unroll
  for (int i = 0; i < 8; ++i)
#pragma unroll
    for (int j = 0; j < 4; ++j) acc[i][j] = (f32x4){0.f, 0.f, 0.f, 0.f};

  // prologue: A(0),B(0) -> dbuf0; B(1) -> dbuf1.B  (A(1) staged at P0/P1)
  stA(0, 0, 0, 0); stA(0, 0, 0, 1); stA(0, 0, 1, 0); stA(0, 0, 1, 1);
  stB(0, 0, 0, 0); stB(0, 0, 0, 1); stB(0, 0, 1, 0); stB(0, 0, 1, 1);
  stB(1, 1, 0, 0); stB(1, 1, 0, 1); stB(1, 1, 1, 0); stB(1, 1, 1, 1);
  asm volatile("s_waitcnt vmcnt(4)" ::: "memory");
  __builtin_amdgcn_s_barrier();
  __builtin_amdgcn_sched_barrier(0);

#pragma unroll 1
  for (int it = 0; it < NITER; ++it) {
    const bool nl = (it < NITER - 1);
    const int t1 = 2 * it + 1;
    short8 bfr[8];
#pragma unroll
    for (int ph = 0; ph < 8; ++ph) {
      const int g  = ph & 3;
      const int db = ph >> 2;                      // dbuf being computed
      const unsigned short* Ab = Al + db * 16384;
      const unsigned short* Bb = Bl + db * 16384;

      // --- stage one half-tile (dead-region schedule) ---
      if      (ph == 0) { stA(t1, 1, 0, 0); stA(t1, 1, 0, 1); }
      else if (ph == 1) { stA(t1, 1, 1, 0); stA(t1, 1, 1, 1); }
      else if (ph == 2) { if (nl) { stB(t1 + 1, 0, 0, 0); stB(t1 + 1, 0, 0, 1); } }
      else if (ph == 3) { if (nl) { stB(t1 + 1, 0, 1, 0); stB(t1 + 1, 0, 1, 1); } }
      else if (ph == 4) { if (nl) { stA(t1 + 1, 0, 0, 0); stA(t1 + 1, 0, 0, 1); } }
      else if (ph == 5) { if (nl) { stA(t1 + 1, 0, 1, 0); stA(t1 + 1, 0, 1, 1); } }
      else if (ph == 6) { if (nl) { stB(t1 + 2, 1, 0, 0); stB(t1 + 2, 1, 0, 1); } }
      else              { if (nl) { stB(t1 + 2, 1, 1, 0); stB(t1 + 2, 1, 1, 1); } }

      // --- ds reads: A quadrant every phase; B once per K-tile ---
      short8 af[2][2];
#pragma unroll
      for (int q = 0; q < 2; ++q)
#pragma unroll
        for (int ks = 0; ks < 2; ++ks)
          af[q][ks] = *(const short8*)(Ab + arow0 + (2 * g + q) * 1024 + ksw[ks]);
      if (g == 0) {
#pragma unroll
        for (int nf = 0; nf < 4; ++nf)
#pragma unroll
          for (int ks = 0; ks < 2; ++ks)
            bfr[nf * 2 + ks] = *(const short8*)(Bb + brow0 + nf * 1024 + ksw[ks]);
      }

      __builtin_amdgcn_s_barrier();
      asm volatile("s_waitcnt lgkmcnt(0)" ::: "memory");
      __builtin_amdgcn_sched_barrier(0);
      __builtin_amdgcn_s_setprio(1);
#pragma unroll
      for (int ks = 0; ks < 2; ++ks)
#pragma unroll
        for (int q = 0; q < 2; ++q)
#pragma unroll
          for (int nf = 0; nf < 4; ++nf)
            acc[2 * g + q][nf] = __builtin_amdgcn_mfma_f32_16x16x32_bf16(
                af[q][ks], bfr[nf * 2 + ks], acc[2 * g + q][nf], 0, 0, 0);
      __builtin_amdgcn_s_setprio(0);

      if (ph == 3) {
        if (nl) asm volatile("s_waitcnt vmcnt(4)" ::: "memory");
        else    asm volatile("s_waitcnt vmcnt(0)" ::: "memory");
      } else if (ph == 7) {
        if (nl) asm volatile("s_waitcnt vmcnt(4)" ::: "memory");
      }
      __builtin_amdgcn_s_barrier();
    }
  }

  // ---- epilogue: route by segment; all outputs bf16
  const int seg = bn >> 11;                        // 0:q 1:k 2:v
  const float* bp = (seg == 0) ? bq : (seg == 1) ? bk : bv;
  float bias_j[4];
#pragma unroll
  for (int j = 0; j < 4; ++j)
    bias_j[j] = bp[(bn + wc * 64 + j * 16 + frow) & 2047];
  const int er = (lane >> 4) * 4;
  unsigned short* dst = (seg == 0) ? qb : kvb;
  const size_t rstride = (seg == 0) ? 2048 : 4096;
  const int coff = (seg == 2) ? 2048 : 0;
#pragma unroll
  for (int I = 0; I < 8; ++I) {
    int row = bm + wr * 128 + I * 16 + er;
#pragma unroll
    for (int j = 0; j < 4; ++j) {
      int col = (bn + wc * 64 + j * 16 + frow) & 2047;
#pragma unroll
      for (int r = 0; r < 4; ++r) {
        float val = acc[I][j][r] + bias_j[j];
        dst[(size_t)(row + r) * rstride + coff + col] = f2bf(val);
      }
    }
  }
}

// ------------------------------------------------------------- FFT core ---
// 2048-pt FFT, 256 threads, radix 8-8-8-4 macro-stages, register butterflies.
__device__ __forceinline__ int XS(int i){ return i ^ (((i >> 5) ^ (i >> 10)) & 31); }
__device__ __forceinline__ int TS(int i){ return i ^ ((i >> 5) & 31); }

__device__ __forceinline__ float2 mulmi(float2 w){ return mkf2(w.y, -w.x); }   // w * (-i)
__device__ __forceinline__ float2 mulw8(float2 w){                              // w * e^{-i pi/4}
  const float c = 0.70710678118654752f;
  return mkf2(c * (w.x + w.y), c * (w.y - w.x));
}
__device__ __forceinline__ void bfly(float2& a, float2& b, float2 w){
  float2 v = cmulf(w, b);
  b = mkf2(a.x - v.x, a.y - v.y);
  a = mkf2(a.x + v.x, a.y + v.y);
}
__device__ __forceinline__ void bflyc(float2& a, float2& b, float2 w){
  float2 d = mkf2(a.x - b.x, a.y - b.y);
  a = mkf2(a.x + b.x, a.y + b.y);
  b = mkf2(fmaf(d.x, w.x, d.y * w.y), fmaf(d.y, w.x, -d.x * w.y));  // d * conj(w)
}

__device__ __forceinline__ void fwd8(float2 e[8], float2 wA, float2 wB0, float2 wC0){
  bfly(e[0], e[1], wA); bfly(e[2], e[3], wA); bfly(e[4], e[5], wA); bfly(e[6], e[7], wA);
  float2 wB1 = mulmi(wB0);
  bfly(e[0], e[2], wB0); bfly(e[1], e[3], wB1); bfly(e[4], e[6], wB0); bfly(e[5], e[7], wB1);
  float2 wC1 = mulw8(wC0), wC2 = mulmi(wC0), wC3 = mulmi(wC1);
  bfly(e[0], e[4], wC0); bfly(e[1], e[5], wC1); bfly(e[2], e[6], wC2); bfly(e[3], e[7], wC3);
}
__device__ __forceinline__ void inv8(float2 e[8], float2 wA, float2 wB0, float2 wC0){
  float2 wC1 = mulw8(wC0), wC2 = mulmi(wC0), wC3 = mulmi(wC1);
  bflyc(e[0], e[4], wC0); bflyc(e[1], e[5], wC1); bflyc(e[2], e[6], wC2); bflyc(e[3], e[7], wC3);
  float2 wB1 = mulmi(wB0);
  bflyc(e[0], e[2], wB0); bflyc(e[1], e[3], wB1); bflyc(e[4], e[6], wB0); bflyc(e[5], e[7], wB1);
  bflyc(e[0], e[1], wA); bflyc(e[2], e[3], wA); bflyc(e[4], e[5], wA); bflyc(e[6], e[7], wA);
}

__device__ __forceinline__ float2 twld(const float* twr, const float* twi, int i){
  int s = TS(i);
  return mkf2(twr[s], twi[s]);
}

__device__ void fft_fwd(float2* X, const float* twr, const float* twi, int t)
{
  const float2 one = mkf2(1.f, 0.f);
  {                                   // MS1
    int b = 8 * t;
    float2 e[8];
#pragma unroll
    for (int r = 0; r < 8; ++r) e[r] = X[XS(b + r)];
    fwd8(e, one, one, one);
#pragma unroll
    for (int r = 0; r < 8; ++r) X[XS(b + r)] = e[r];
  }
  __syncthreads();
  {                                   // MS2
    int u = t >> 5, b = 64 * (t & 31) + u;
    float2 e[8];
#pragma unroll
    for (int r = 0; r < 8; ++r) e[r] = X[XS(b + 8 * r)];
    fwd8(e, twld(twr,twi,128*u), twld(twr,twi,64*u), twld(twr,twi,32*u));
#pragma unroll
    for (int r = 0; r < 8; ++r) X[XS(b + 8 * r)] = e[r];
  }
  __syncthreads();
  {                                   // MS3
    int u = t & 63, b = 512 * (t >> 6) + u;
    float2 e[8];
#pragma unroll
    for (int r = 0; r < 8; ++r) e[r] = X[XS(b + 64 * r)];
    fwd8(e, twld(twr,twi,16*u), twld(twr,twi,8*u), twld(twr,twi,4*u));
#pragma unroll
    for (int r = 0; r < 8; ++r) X[XS(b + 64 * r)] = e[r];
  }
  __syncthreads();
#pragma unroll
  for (int h = 0; h < 2; ++h) {       // MS4: radix-4
    int u = t + 256 * h;
    float2 f[4];
#pragma unroll
    for (int r = 0; r < 4; ++r) f[r] = X[XS(u + 512 * r)];
    float2 wA = twld(twr,twi,2*u), wB0 = twld(twr,twi,u), wB1 = mulmi(wB0);
    bfly(f[0], f[1], wA);  bfly(f[2], f[3], wA);
    bfly(f[0], f[2], wB0); bfly(f[1], f[3], wB1);
#pragma unroll
    for (int r = 0; r < 4; ++r) X[XS(u + 512 * r)] = f[r];
  }
  __syncthreads();
}

__device__ void fft_inv(float2* X, const float* twr, const float* twi, int t)
{
  const float2 one = mkf2(1.f, 0.f);
#pragma unroll
  for (int h = 0; h < 2; ++h) {       // MS4'
    int u = t + 256 * h;
    float2 f[4];
#pragma unroll
    for (int r = 0; r < 4; ++r) f[r] = X[XS(u + 512 * r)];
    float2 wA = twld(twr,twi,2*u), wB0 = twld(twr,twi,u), wB1 = mulmi(wB0);
    bflyc(f[0], f[2], wB0); bflyc(f[1], f[3], wB1);
    bflyc(f[0], f[1], wA);  bflyc(f[2], f[3], wA);
#pragma unroll
    for (int r = 0; r < 4; ++r) X[XS(u + 512 * r)] = f[r];
  }
  __syncthreads();
  {                                   // MS3'
    int u = t & 63, b = 512 * (t >> 6) + u;
    float2 e[8];
#pragma unroll
    for (int r = 0; r < 8; ++r) e[r] = X[XS(b + 64 * r)];
    inv8(e, twld(twr,twi,16*u), twld(twr,twi,8*u), twld(twr,twi,4*u));
#pragma unroll
    for (int r = 0; r < 8; ++r) X[XS(b + 64 * r)] = e[r];
  }
  __syncthreads();
  {                                   // MS2'
    int u = t >> 5, b = 64 * (t & 31) + u;
    float2 e[8];
#pragma unroll
    for (int r = 0; r < 8; ++r) e[r] = X[XS(b + 8 * r)];
    inv8(e, twld(twr,twi,128*u), twld(twr,twi,64*u), twld(twr,twi,32*u));
#pragma unroll
    for (int r = 0; r < 8; ++r) X[XS(b + 8 * r)] = e[r];
  }
  __syncthreads();
  {                                   // MS1'
    int b = 8 * t;
    float2 e[8];
#pragma unroll
    for (int r = 0; r < 8; ++r) e[r] = X[XS(b + r)];
    inv8(e, one, one, one);
#pragma unroll
    for (int r = 0; r < 8; ++r) X[XS(b + r)] = e[r];
  }
  __syncthreads();
}

// ------------------------------------------------------- twiddle table ----
__global__ __launch_bounds__(256)
void twiddle_init(float2* __restrict__ twg)
{
  int i = blockIdx.x * 256 + threadIdx.x;
  if (i < HALF_D) {
    float sv, cv;
    sincosf(-6.283185307179586f * (float)i / (float)D_DIM, &sv, &cv);
    twg[i] = mkf2(cv, sv);
  }
}

// ---------------------------------------------------------- FFT(k,v)·mul --
// kvb row r: [k bf16 x2048 | v bf16 x2048]. One complex FFT of (k + i·v)
// recovers both spectra; writes packed half-spectrum of unit(Fk)·unit(Fv)
// as bf16 pairs (re,im) into the first 2048 ushorts of the row slot.
__global__ __launch_bounds__(256)
void fftkv_kernel(unsigned short* __restrict__ kvb, const float2* __restrict__ twg)
{
  __shared__ float2 X[D_DIM];
  __shared__ float twr[HALF_D], twi[HALF_D];
  const int t = threadIdx.x;
  const size_t row = blockIdx.x;
  const unsigned short* kvrow = kvb + row * 4096;

  for (int i = t; i < HALF_D; i += 256) {
    float2 w = twg[i]; int s = TS(i); twr[s] = w.x; twi[s] = w.y;
  }
  {
    int i0 = t * 8;
    ushort8 k8 = *(const ushort8*)(kvrow + i0);
    ushort8 v8 = *(const ushort8*)(kvrow + 2048 + i0);
#pragma unroll
    for (int r = 0; r < 8; ++r) {
      int i = i0 + r;
      int p = __brev((unsigned)i) >> 21;
      X[XS(p)] = mkf2(bf2f(k8[r]), bf2f(v8[r]));
    }
  }
  __syncthreads();
  fft_fwd(X, twr, twi, t);

  unsigned int* outp = (unsigned int*)(kvb + row * 4096);
  for (int d = t; d < HALF_D; d += 256) {
    float2 p;
    if (d == 0) {
      float2 z0 = X[XS(0)], zn = X[XS(HALF_D)];
      float k0 = z0.x, v0 = z0.y, kn = zn.x, vn = zn.y;
      float p0 = (k0 / (fabsf(k0) + EPS_)) * (v0 / (fabsf(v0) + EPS_));
      float pn = (kn / (fabsf(kn) + EPS_)) * (vn / (fabsf(vn) + EPS_));
      p = mkf2(p0, pn);
    } else {
      float2 A = X[XS(d)];
      float2 Bc = X[XS(D_DIM - d)];
      float2 Bj = mkf2(Bc.x, -Bc.y);
      float2 Fk = mkf2(0.5f * (A.x + Bj.x), 0.5f * (A.y + Bj.y));
      float2 tt = mkf2(0.5f * (A.x - Bj.x), 0.5f * (A.y - Bj.y));
      float2 Fv = mkf2(tt.y, -tt.x);
      float sa = 1.f / (sqrtf(Fk.x*Fk.x + Fk.y*Fk.y) + EPS_);
      float sb = 1.f / (sqrtf(Fv.x*Fv.x + Fv.y*Fv.y) + EPS_);
      p = cmulf(Fk, Fv);
      float sc = sa * sb;
      p.x *= sc; p.y *= sc;
    }
    outp[d] = (unsigned)f2bf(p.x) | ((unsigned)f2bf(p.y) << 16);
  }
}

// --------------------------------------------------------------- scan -----
// Spectra stored as bf16 pairs, 4 bins (16B) per thread; f32 accumulators
// and f32 chunk partials. part layout [b][chunk][1024] float2.
__global__ __launch_bounds__(256)
void scan_partial(const unsigned short* __restrict__ kvb, float2* __restrict__ part)
{
  int gid = blockIdx.x * 256 + threadIdx.x;        // 0 .. 32767
  int q4 = gid & 255;
  int chunk = (gid >> 8) & (NCHUNK - 1);
  int b = gid >> 14;
  const unsigned short* p = kvb + (size_t)(b * S_DIM + chunk * CHLEN) * 4096 + q4 * 8;
  float ar[4] = {0,0,0,0}, ai[4] = {0,0,0,0};
  for (int s = 0; s < CHLEN; ++s) {
    ushort8 v = *(const ushort8*)(p + (size_t)s * 4096);
#pragma unroll
    for (int e = 0; e < 4; ++e) { ar[e] += bf2f(v[2*e]); ai[e] += bf2f(v[2*e+1]); }
  }
  float2* pp = part + (size_t)(b * NCHUNK + chunk) * HALF_D + q4 * 4;
#pragma unroll
  for (int e = 0; e < 4; ++e) pp[e] = mkf2(ar[e], ai[e]);
}

__global__ __launch_bounds__(256)
void scan_offsets(float2* __restrict__ part)
{
  int gid = blockIdx.x * 256 + threadIdx.x;        // 0 .. B*HALF_D-1
  int d = gid & (HALF_D - 1);
  int b = gid >> 10;
  float2* p = part + (size_t)b * (NCHUNK * HALF_D) + d;
  float2 acc = mkf2(0.f, 0.f);
  for (int c = 0; c < NCHUNK; ++c) {
    float2 v = p[(size_t)c * HALF_D];
    p[(size_t)c * HALF_D] = acc;                   // exclusive prefix
    acc.x += v.x; acc.y += v.y;
  }
}

__global__ __launch_bounds__(256)
void scan_apply(unsigned short* __restrict__ kvb, const float2* __restrict__ part)
{
  int gid = blockIdx.x * 256 + threadIdx.x;
  int q4 = gid & 255;
  int chunk = (gid >> 8) & (NCHUNK - 1);
  int b = gid >> 14;
  unsigned short* p = kvb + (size_t)(b * S_DIM + chunk * CHLEN) * 4096 + q4 * 8;
  const float2* pp = part + (size_t)(b * NCHUNK + chunk) * HALF_D + q4 * 4;
  float ar[4], ai[4];
#pragma unroll
  for (int e = 0; e < 4; ++e) { float2 v = pp[e]; ar[e] = v.x; ai[e] = v.y; }
  for (int s = 0; s < CHLEN; ++s) {
    ushort8 v = *(const ushort8*)(p + (size_t)s * 4096);
    ushort8 o;
#pragma unroll
    for (int e = 0; e < 4; ++e) {
      ar[e] += bf2f(v[2*e]); ai[e] += bf2f(v[2*e+1]);
      o[2*e] = f2bf(ar[e]); o[2*e+1] = f2bf(ai[e]);
    }
    *(ushort8*)(p + (size_t)s * 4096) = o;
  }
}

// --------------------------------------------------------------- final ----
// TWO rows per block via real-FFT packing:
//   Z = FFT(q0 + i q1);  Fq0 = (Z+conj(Zrev))/2,  Fq1 = -i(Z-conj(Zrev))/2
//   G0 = conj(Fq0)·M0,  G1 = conj(Fq1)·M1   (Gk conj-symmetric, yk real)
//   y = ifft(G0 + i G1);  out0 = Re(y), out1 = Im(y).
// Halves FFT count per row vs the 1-row version.
__global__ __launch_bounds__(256)
void final_kernel(const unsigned short* __restrict__ qb,
                  const unsigned short* __restrict__ kvb,
                  const float* __restrict__ base, const float* __restrict__ gate,
                  const float2* __restrict__ twg, float* __restrict__ out)
{
  __shared__ float2 X[D_DIM];
  __shared__ float twr[HALF_D], twi[HALF_D];
  const int t = threadIdx.x;
  const size_t row0 = (size_t)blockIdx.x * 2;
  const unsigned short* qrow = qb + row0 * 2048;   // rows row0, row0+1
  const unsigned short* m0 = kvb + row0 * 4096;    // bf16 (re,im) pairs
  const unsigned short* m1 = m0 + 4096;

  for (int i = t; i < HALF_D; i += 256) {
    float2 w = twg[i]; int s = TS(i); twr[s] = w.x; twi[s] = w.y;
  }
  {
    int i0 = t * 8;
    ushort8 q0 = *(const ushort8*)(qrow + i0);
    ushort8 q1 = *(const ushort8*)(qrow + 2048 + i0);
#pragma unroll
    for (int r = 0; r < 8; ++r) {
      int i = i0 + r;
      int p = __brev((unsigned)i) >> 21;
      X[XS(p)] = mkf2(bf2f(q0[r]), bf2f(q1[r]));
    }
  }
  __syncthreads();
  fft_fwd(X, twr, twi, t);

  for (int d = t; d < HALF_D; d += 256) {
    if (d == 0) {
      // bins 0 and N/2: Fq0 = .x, Fq1 = .y (all real); M packed (M[0],M[N/2])
      float2 z0 = X[XS(0)], zn = X[XS(HALF_D)];
      float M00 = bf2f(m0[0]), M0N = bf2f(m0[1]);
      float M10 = bf2f(m1[0]), M1N = bf2f(m1[1]);
      X[XS(0)]      = mkf2(z0.x * M00, z0.y * M10);
      X[XS(HALF_D)] = mkf2(zn.x * M0N, zn.y * M1N);
    } else {
      float2 Zd = X[XS(d)];
      float2 Zn = X[XS(D_DIM - d)];
      float2 Fq0 = mkf2(0.5f * (Zd.x + Zn.x), 0.5f * (Zd.y - Zn.y));
      float2 td  = mkf2(0.5f * (Zd.x - Zn.x), 0.5f * (Zd.y + Zn.y));
      float2 Fq1 = mkf2(td.y, -td.x);              // -i * td
      float2 M0d = mkf2(bf2f(m0[2*d]), bf2f(m0[2*d+1]));
      float2 M1d = mkf2(bf2f(m1[2*d]), bf2f(m1[2*d+1]));
      // Gk = conj(Fqk) * Mkd
      float2 G0 = mkf2(Fq0.x*M0d.x + Fq0.y*M0d.y, Fq0.x*M0d.y - Fq0.y*M0d.x);
      float2 G1 = mkf2(Fq1.x*M1d.x + Fq1.y*M1d.y, Fq1.x*M1d.y - Fq1.y*M1d.x);
      // W[d] = G0 + i G1;  W[N-d] = conj(G0) + i conj(G1)
      X[XS(d)]         = mkf2(G0.x - G1.y, G0.y + G1.x);
      X[XS(D_DIM - d)] = mkf2(G0.x + G1.y, G1.x - G0.y);
    }
  }
  __syncthreads();
  fft_inv(X, twr, twi, t);

  const float gv = gate[0] * (1.f / (float)D_DIM);
  const float* brow = base + row0 * 2048;
  float* orow = out + row0 * 2048;
  for (int i = t; i < D_DIM; i += 256) {
    int p = __brev((unsigned)i) >> 21;
    float2 y = X[XS(p)];
    orow[i]        = brow[i]        + gv * y.x;
    orow[2048 + i] = brow[2048 + i] + gv * y.y;
  }
}

// ------------------------------------------------------------ launcher ----
extern "C" void kernel_launch(void* const* d_in, const int* in_sizes, int n_in,
                              void* d_out, int out_size, void* d_ws, size_t ws_size,
                              hipStream_t stream)
{
  const float* hs   = (const float*)d_in[0];
  const float* base = (const float*)d_in[1];
  const float* Wq   = (const float*)d_in[2];
  const float* bq   = (const float*)d_in[3];
  const float* Wk   = (const float*)d_in[4];
  const float* bk   = (const float*)d_in[5];
  const float* Wv   = (const float*)d_in[6];
  const float* bv   = (const float*)d_in[7];
  const float* gate = (const float*)d_in[8];
  float* out  = (float*)d_out;

  // workspace layout:
  //   hsb  bf16 [8192][2048]   (first 8KB reused as twiddle table post-GEMM)
  //   wqb|wkb|wvb bf16 [6144][2048] contiguous (fused weight)
  //   kvb  [8192] x 8KB rows: [k bf16 | v bf16] -> bf16 packed Fkv/Fmem
  //   qb   bf16 [8192][2048]
  //   part f32x2 [2][64][1024]
  char* ws = (char*)d_ws;
  unsigned short* hsb = (unsigned short*)ws;
  unsigned short* wqb = (unsigned short*)(ws + 33554432);
  unsigned short* kvb = (unsigned short*)(ws + 58720256);
  unsigned short* qb  = (unsigned short*)(ws + 58720256 + 67108864);
  float2* part = (float2*)(ws + 58720256 + 67108864 + 33554432);
  float2* twg  = (float2*)ws;   // overwrites hsb AFTER the GEMM consumed it

  {
    constexpr int n8 = (NROW * D_DIM) / 8;        // 2097152
    constexpr int w8 = (D_DIM * D_DIM) / 8;       // 524288
    cvt_inputs<<<(n8 + 3 * w8) / 256, 256, 0, stream>>>(hs, Wq, Wk, Wv, hsb, wqb);
  }

  gemm_fused<<<768, 512, 0, stream>>>(hsb, wqb, bq, bk, bv, qb, kvb);

  twiddle_init<<<4, 256, 0, stream>>>(twg);

  fftkv_kernel<<<NROW, 256, 0, stream>>>(kvb, twg);

  scan_partial<<<128, 256, 0, stream>>>(kvb, part);
  scan_offsets<<<(B_DIM * HALF_D) / 256, 256, 0, stream>>>(part);
  scan_apply<<<128, 256, 0, stream>>>(kvb, part);

  final_kernel<<<NROW / 2, 256, 0, stream>>>(qb, kvb, base, gate, twg, out);
}